// Round 8
// baseline (224.791 us; speedup 1.0000x reference)
//
#include <hip/hip_runtime.h>

#define EPS 1e-5f
constexpr int NN  = 100000;   // nodes
constexpr int NE  = 1600000;  // edges
constexpr int R   = 8;
constexpr int NBK = NN / 16;  // 6250 dst-buckets (one per fused block)
constexpr int CAP = 512;      // bucket capacity (mean 256, sd 16 -> 16 sigma)
constexpr int CHUNK  = 2048;  // edges per scatter chunk
constexpr int NCHUNK = (NE + CHUNK - 1) / CHUNK;  // 782

typedef _Float16 half8 __attribute__((ext_vector_type(8)));
typedef float f32x4 __attribute__((ext_vector_type(4)));

static __device__ inline float h2f(unsigned int u) {
    _Float16 h = __builtin_bit_cast(_Float16, (unsigned short)u);
    return (float)h;
}
static __device__ inline unsigned short f2h(float f) {
    _Float16 h = (_Float16)f;
    return __builtin_bit_cast(unsigned short, h);
}
static __device__ inline int ntload(const int* p) {
    return __builtin_nontemporal_load(p);   // no L2 allocation: keep the edge
}                                           // stream from evicting sedge lines

// ---------------- x0 = bn32(emb[n_id]) -> fp16 ----------------
__global__ __launch_bounds__(256) void compute_x0(
    const int* __restrict__ n_id, const float* __restrict__ emb,
    const float* __restrict__ g, const float* __restrict__ b,
    const float* __restrict__ m, const float* __restrict__ v,
    unsigned int* __restrict__ x0)   // [NN*16] uints = [NN,32] fp16
{
    int idx = blockIdx.x * 256 + threadIdx.x;
    if (idx >= NN * 16) return;
    int i = idx >> 4, c = (idx & 15) * 2;
    int nid = n_id[i];
    float2 e = *reinterpret_cast<const float2*>(&emb[nid * 32 + c]);
    float s0 = g[c]     / sqrtf(v[c]     + EPS);
    float s1 = g[c + 1] / sqrtf(v[c + 1] + EPS);
    float y0 = (e.x - m[c])     * s0 + b[c];
    float y1 = (e.y - m[c + 1]) * s1 + b[c + 1];
    x0[idx] = (unsigned int)f2h(y0) | ((unsigned int)f2h(y1) << 16);
}

// ---------------- XCD-class-filtered bucket scatter ----------------
// class = blockIdx&7 (round-robins onto XCDs); block handles chunk blockIdx>>3
// and emits only edges whose bucket&7 == class -> each sedge line has a
// single writer XCD. nt-loads keep the read stream out of L2 so partially
// filled sedge lines survive until full (write-amp ~1x).
__global__ __launch_bounds__(256) void scatter_edges(
    const int* __restrict__ ei, const int* __restrict__ et,
    int* __restrict__ cnt, unsigned int* __restrict__ sedge)
{
    const int cls   = blockIdx.x & 7;
    const int base  = (blockIdx.x >> 3) * CHUNK;
#pragma unroll
    for (int j = 0; j < CHUNK / 256; ++j) {
        int e = base + j * 256 + threadIdx.x;
        if (e >= NE) break;
        int dst = ntload(&ei[NE + e]);
        int b = dst >> 4;
        if ((b & 7) != cls) continue;
        unsigned payload = (unsigned)ntload(&ei[e]) |
                           ((unsigned)ntload(&et[e]) << 20) |
                           ((unsigned)(dst & 15) << 23);
        int pos = atomicAdd(&cnt[b], 1);
        if (pos < CAP) sedge[(size_t)b * CAP + pos] = payload;
    }
}

// ---------------- weight pack: B[K,64] fp32 -> fp16 fragments ----------------
template <int CIN>
__global__ __launch_bounds__(256) void pack_B(
    const float* __restrict__ Wrel,   // [R*CIN, 64]
    const float* __restrict__ Wroot,  // [CIN, 64]
    unsigned short* __restrict__ Bp)
{
    constexpr int K = 9 * CIN, KS = K / 32;
    int idx = blockIdx.x * 256 + threadIdx.x;
    if (idx >= 4 * KS * 64) return;
    int l = idx & 63;
    int rest = idx >> 6;
    int s = rest % KS;
    int t = rest / KS;
    int kb = s * 32 + (l >> 4) * 8;
    int col = t * 16 + (l & 15);
    unsigned short* dst = &Bp[(size_t)idx * 8];
#pragma unroll
    for (int j = 0; j < 8; ++j) {
        int k = kb + j;
        float w = (k < CIN) ? Wroot[k * 64 + col]
                            : Wrel[(size_t)(k - CIN) * 64 + col];
        dst[j] = f2h(w);
    }
}

// ---------------- fold BN into scale/shift ----------------
__global__ __launch_bounds__(64) void prep_scales(
    const float* g1, const float* b1, const float* m1, const float* v1,
    float* sc1, float* sh1,
    const float* g2, const float* b2, const float* m2, const float* v2,
    float* sc2, float* sh2)
{
    int o = threadIdx.x;
    float s1 = g1[o] / sqrtf(v1[o] + EPS);
    sc1[o] = s1;
    sh1[o] = b1[o] - m1[o] * s1;
    float s2 = g2[o] / sqrtf(v2[o] + EPS);
    sc2[o] = s2;
    sh2[o] = b2[o] - m2[o] * s2;
}

// ---------------- fused: LDS sort + batched gather (run-length mean) + MFMA ----
template <int CIN, bool APPLY_RELU, bool OUT_F16>
__global__ __launch_bounds__(256) void fused_layer(
    const unsigned short* __restrict__ x,   // [N, CIN] fp16
    const unsigned int* __restrict__ sedge, // [NBK*CAP] bucketed edges
    const int* __restrict__ bcnt,           // [NBK] bucket counts
    const unsigned short* __restrict__ Bp,  // packed fp16 fragments
    const float* __restrict__ bias,         // [64]
    const float* __restrict__ scale, const float* __restrict__ shift,
    void* __restrict__ outv)                // [N,64] fp16 or fp32
{
    constexpr int NB  = 16;            // nodes per block (= MFMA M)
    constexpr int K   = 9 * CIN;       // 288 or 576
    constexpr int KS  = K / 32;        // MFMA K-steps
    constexpr int Kp  = K + 8;         // padded row stride (shorts)
    constexpr int VEC = CIN / 16;      // channels per lane: 2 or 4

    __shared__ unsigned short As[NB][Kp];
    __shared__ unsigned int   raw[CAP];
    __shared__ unsigned int   srt[CAP];
    __shared__ int cnt128[128];
    __shared__ int segoff[129];
    __shared__ int cur[128];

    const int node0 = blockIdx.x * NB;
    const int tid = threadIdx.x;
    const int nloc = min(bcnt[blockIdx.x], CAP);

    // ---- phase 0a: zero sort counters + copy root rows + zero agg region ----
    if (tid < 128) cnt128[tid] = 0;
    for (int t = tid; t < NB * (CIN / 4); t += 256) {
        int g = t / (CIN / 4), q = (t % (CIN / 4)) * 4;
        *reinterpret_cast<uint2*>(&As[g][q]) =
            *reinterpret_cast<const uint2*>(&x[(size_t)(node0 + g) * CIN + q]);
    }
    {
        uint4 z = {0u, 0u, 0u, 0u};
        for (int t = tid; t < NB * CIN; t += 256) {
            int g = t / CIN, q = (t % CIN) * 8;
            *reinterpret_cast<uint4*>(&As[g][CIN + q]) = z;
        }
    }
    __syncthreads();

    // ---- phase 0b: stage edges + count per (g,r) key ----
    for (int t = tid; t < nloc; t += 256) {
        unsigned se = sedge[(size_t)blockIdx.x * CAP + t];
        raw[t] = se;
        atomicAdd(&cnt128[(se >> 20) & 127], 1);
    }
    __syncthreads();

    // ---- phase 0c: scan 128 counters (Hillis-Steele, in place) ----
    for (int d = 1; d < 128; d <<= 1) {
        int v = 0;
        if (tid < 128 && tid >= d) v = cnt128[tid - d];
        __syncthreads();
        if (tid < 128) cnt128[tid] += v;
        __syncthreads();
    }
    if (tid < 128) segoff[tid + 1] = cnt128[tid];
    if (tid == 0) segoff[0] = 0;
    __syncthreads();
    if (tid < 128) cur[tid] = segoff[tid];
    __syncthreads();

    // ---- phase 0d: place into sorted order ----
    for (int t = tid; t < nloc; t += 256) {
        unsigned se = raw[t];
        int k = (se >> 20) & 127;
        int slot = atomicAdd(&cur[k], 1);
        srt[slot] = se;
    }
    __syncthreads();

    // ---- phase 1: per-node span walk, 4-batched gathers, run-length mean ----
    {
        const int lx = tid & 15;          // 16 lanes per node
        const int g  = tid >> 4;          // node slot 0..15
        const int c0 = lx * VEC;
        const int s = segoff[g * 8];
        const int e = segoff[g * 8 + 8];

        float a0 = 0.f, a1 = 0.f, a2 = 0.f, a3 = 0.f;
        int cur_r = -1, cnt = 0;

        auto flushrun = [&]() {
            if (cnt > 0) {
                float inv = 1.0f / (float)cnt;
                if constexpr (VEC == 4) {
                    uint2 pk;
                    pk.x = (unsigned)f2h(a0 * inv) | ((unsigned)f2h(a1 * inv) << 16);
                    pk.y = (unsigned)f2h(a2 * inv) | ((unsigned)f2h(a3 * inv) << 16);
                    *reinterpret_cast<uint2*>(&As[g][CIN + cur_r * CIN + c0]) = pk;
                } else {
                    unsigned pk = (unsigned)f2h(a0 * inv) |
                                  ((unsigned)f2h(a1 * inv) << 16);
                    *reinterpret_cast<unsigned*>(&As[g][CIN + cur_r * CIN + c0]) = pk;
                }
                a0 = a1 = a2 = a3 = 0.f;
            }
        };
        auto proc = [&](unsigned se, uint2 xv) {
            int r = (int)((se >> 20) & 7);
            if (r != cur_r) { flushrun(); cur_r = r; cnt = 0; }
            a0 += h2f(xv.x & 0xffff);
            a1 += h2f(xv.x >> 16);
            if constexpr (VEC == 4) {
                a2 += h2f(xv.y & 0xffff);
                a3 += h2f(xv.y >> 16);
            }
            ++cnt;
        };
        auto loadx = [&](unsigned se) -> uint2 {
            size_t base = (size_t)(se & 0xFFFFF) * CIN + c0;
            if constexpr (VEC == 4)
                return *reinterpret_cast<const uint2*>(&x[base]);
            else {
                uint2 r2; r2.x = *reinterpret_cast<const unsigned*>(&x[base]); r2.y = 0u;
                return r2;
            }
        };

        int j = s;
        for (; j + 4 <= e; j += 4) {
            unsigned se0 = srt[j],     se1 = srt[j + 1];
            unsigned se2 = srt[j + 2], se3 = srt[j + 3];
            uint2 x0v = loadx(se0);
            uint2 x1v = loadx(se1);
            uint2 x2v = loadx(se2);
            uint2 x3v = loadx(se3);
            proc(se0, x0v); proc(se1, x1v); proc(se2, x2v); proc(se3, x3v);
        }
        for (; j < e; ++j) {
            unsigned se0 = srt[j];
            proc(se0, loadx(se0));
        }
        flushrun();
    }
    __syncthreads();

    // ---- phase 2: [16 x K] * [K x 64] via mfma_f32_16x16x32_f16 ----
    const int lane = tid & 63, wave = tid >> 6;   // wave owns 16-col N-tile
    const int arow = lane & 15;
    const int kb   = (lane >> 4) * 8;
    f32x4 acc = {0.f, 0.f, 0.f, 0.f};
    const unsigned short* a_ptr = &As[arow][kb];
    const unsigned short* b_ptr = &Bp[((size_t)(wave * KS) * 64 + lane) * 8];
#pragma unroll
    for (int ks = 0; ks < KS; ++ks) {
        half8 a = *reinterpret_cast<const half8*>(a_ptr + ks * 32);
        half8 b = *reinterpret_cast<const half8*>(b_ptr + (size_t)ks * 64 * 8);
        acc = __builtin_amdgcn_mfma_f32_16x16x32_f16(a, b, acc, 0, 0, 0);
    }

    // ---- epilogue: bias, (relu), BN; C layout: col=lane&15, row=(lane>>4)*4+r
    const int o = wave * 16 + (lane & 15);
    const float sc = scale[o], sh = shift[o], bi = bias[o];
#pragma unroll
    for (int r = 0; r < 4; ++r) {
        int nrow = (lane >> 4) * 4 + r;
        float t = acc[r] + bi;
        if (APPLY_RELU) t = fmaxf(t, 0.0f);
        t = t * sc + sh;
        size_t oidx = (size_t)(node0 + nrow) * 64 + o;
        if (OUT_F16) ((unsigned short*)outv)[oidx] = f2h(t);
        else         ((float*)outv)[oidx] = t;
    }
}

extern "C" void kernel_launch(void* const* d_in, const int* in_sizes, int n_in,
                              void* d_out, int out_size, void* d_ws, size_t ws_size,
                              hipStream_t stream)
{
    const int*   n_id   = (const int*)d_in[0];
    const int*   ei     = (const int*)d_in[1];   // [2, NE]
    const int*   et     = (const int*)d_in[2];   // [NE]
    const float* emb    = (const float*)d_in[3];
    const float* W1     = (const float*)d_in[4];
    const float* root1  = (const float*)d_in[5];
    const float* b1     = (const float*)d_in[6];
    const float* W2     = (const float*)d_in[7];
    const float* root2  = (const float*)d_in[8];
    const float* b2     = (const float*)d_in[9];
    const float* bn32_g = (const float*)d_in[10];
    const float* bn32_b = (const float*)d_in[11];
    const float* bn32_m = (const float*)d_in[12];
    const float* bn32_v = (const float*)d_in[13];
    const float* bn64_g = (const float*)d_in[14];
    const float* bn64_b = (const float*)d_in[15];
    const float* bn64_m = (const float*)d_in[16];
    const float* bn64_v = (const float*)d_in[17];
    const float* bnb_g  = (const float*)d_in[18];
    const float* bnb_b  = (const float*)d_in[19];
    const float* bnb_m  = (const float*)d_in[20];
    const float* bnb_v  = (const float*)d_in[21];
    float* out = (float*)d_out;

    // workspace layout (all chunks 16B-aligned)
    char* p = (char*)d_ws;
    int* cnt = (int*)p;                        p += (size_t)((NBK + 3) & ~3) * 4;
    unsigned int* sedge = (unsigned int*)p;    p += (size_t)NBK * CAP * 4;
    unsigned short* x0  = (unsigned short*)p;  p += (size_t)NN * 32 * 2;
    unsigned short* h1  = (unsigned short*)p;  p += (size_t)NN * 64 * 2;
    unsigned short* Bp1 = (unsigned short*)p;  p += 4 * 9  * 64 * 8 * 2;
    unsigned short* Bp2 = (unsigned short*)p;  p += 4 * 18 * 64 * 8 * 2;
    float* sc1 = (float*)p;           p += 64 * 4;
    float* sh1 = (float*)p;           p += 64 * 4;
    float* sc2 = (float*)p;           p += 64 * 4;
    float* sh2 = (float*)p;           p += 64 * 4;

    // ---- bucket the edges, XCD-class-filtered (shared by both layers) ----
    hipMemsetAsync(cnt, 0, (size_t)NBK * sizeof(int), stream);
    scatter_edges<<<NCHUNK * 8, 256, 0, stream>>>(ei, et, cnt, sedge);

    // ---- weight/bn prep ----
    prep_scales<<<1, 64, 0, stream>>>(bn64_g, bn64_b, bn64_m, bn64_v, sc1, sh1,
                                      bnb_g, bnb_b, bnb_m, bnb_v, sc2, sh2);
    pack_B<32><<<(4 * 9 * 64 + 255) / 256, 256, 0, stream>>>(W1, root1, Bp1);
    pack_B<64><<<(4 * 18 * 64 + 255) / 256, 256, 0, stream>>>(W2, root2, Bp2);

    // ---- layer 1 ----
    compute_x0<<<(NN * 16 + 255) / 256, 256, 0, stream>>>(
        n_id, emb, bn32_g, bn32_b, bn32_m, bn32_v, (unsigned int*)x0);
    fused_layer<32, true, true><<<NBK, 256, 0, stream>>>(
        x0, sedge, cnt, Bp1, b1, sc1, sh1, h1);

    // ---- layer 2 ----
    fused_layer<64, false, false><<<NBK, 256, 0, stream>>>(
        h1, sedge, cnt, Bp2, b2, sc2, sh2, out);
}

// Round 9
// 160.448 us; speedup vs baseline: 1.4010x; 1.4010x over previous
//
#include <hip/hip_runtime.h>

#define EPS 1e-5f
constexpr int NN  = 100000;   // nodes
constexpr int NE  = 1600000;  // edges
constexpr int R   = 8;
constexpr int NBK = NN / 16;  // 6250 dst-buckets (one per fused block)
constexpr int CAP = 512;      // bucket capacity (mean 256, sd 16)
constexpr int CHUNK  = 2048;  // edges per binner chunk
constexpr int NCHUNK = (NE + CHUNK - 1) / CHUNK;  // 782
constexpr int NBIN   = 98;    // coarse bins of 1024 nodes (64 buckets each)
constexpr int SEGS   = 9;     // refine segments per bin
constexpr int BINCAP = SEGS * CHUNK;  // 18432 (mean 16384, +16 sigma)

typedef _Float16 half8 __attribute__((ext_vector_type(8)));
typedef float f32x4 __attribute__((ext_vector_type(4)));

static __device__ inline float h2f(unsigned int u) {
    _Float16 h = __builtin_bit_cast(_Float16, (unsigned short)u);
    return (float)h;
}
static __device__ inline unsigned short f2h(float f) {
    _Float16 h = (_Float16)f;
    return __builtin_bit_cast(unsigned short, h);
}

// ---------------- x0 = bn32(emb[n_id]) -> fp16 ----------------
__global__ __launch_bounds__(256) void compute_x0(
    const int* __restrict__ n_id, const float* __restrict__ emb,
    const float* __restrict__ g, const float* __restrict__ b,
    const float* __restrict__ m, const float* __restrict__ v,
    unsigned int* __restrict__ x0)   // [NN*16] uints = [NN,32] fp16
{
    int idx = blockIdx.x * 256 + threadIdx.x;
    if (idx >= NN * 16) return;
    int i = idx >> 4, c = (idx & 15) * 2;
    int nid = n_id[i];
    float2 e = *reinterpret_cast<const float2*>(&emb[nid * 32 + c]);
    float s0 = g[c]     / sqrtf(v[c]     + EPS);
    float s1 = g[c + 1] / sqrtf(v[c + 1] + EPS);
    float y0 = (e.x - m[c])     * s0 + b[c];
    float y1 = (e.y - m[c + 1]) * s1 + b[c + 1];
    x0[idx] = (unsigned int)f2h(y0) | ((unsigned int)f2h(y1) << 16);
}

// ---------------- level 1: chunk -> coarse-bin partition (coalesced runs) ----
// payload2 = src(0-16) | r(17-19) | (dst&1023)(20-29)
__global__ __launch_bounds__(256) void binner(
    const int* __restrict__ ei, const int* __restrict__ et,
    int* __restrict__ gcur, unsigned int* __restrict__ binreg)
{
    __shared__ unsigned pay[CHUNK];
    __shared__ unsigned short bof[CHUNK];
    __shared__ unsigned srt[CHUNK];
    __shared__ unsigned short sb[CHUNK];
    __shared__ int hist[NBIN], lstart[NBIN], lcur[NBIN], gbase[NBIN];
    __shared__ int scanbuf[NBIN];

    const int tid = threadIdx.x;
    const int base = blockIdx.x * CHUNK;
    const int n = min(CHUNK, NE - base);

    for (int t = tid; t < NBIN; t += 256) hist[t] = 0;
    __syncthreads();

    for (int t = tid; t < n; t += 256) {
        int e = base + t;
        int dst = ei[NE + e];
        int bin = dst >> 10;
        pay[t] = (unsigned)ei[e] | ((unsigned)et[e] << 17) |
                 ((unsigned)(dst & 1023) << 20);
        bof[t] = (unsigned short)bin;
        atomicAdd(&hist[bin], 1);
    }
    __syncthreads();

    if (tid < NBIN) scanbuf[tid] = hist[tid];
    __syncthreads();
    for (int d = 1; d < NBIN; d <<= 1) {
        int v = 0;
        if (tid < NBIN && tid >= d) v = scanbuf[tid - d];
        __syncthreads();
        if (tid < NBIN) scanbuf[tid] += v;
        __syncthreads();
    }
    if (tid < NBIN) {
        int h = hist[tid];
        int excl = scanbuf[tid] - h;
        lstart[tid] = excl;
        lcur[tid]   = excl;
        gbase[tid]  = (h > 0) ? atomicAdd(&gcur[tid], h) : 0;
    }
    __syncthreads();

    for (int t = tid; t < n; t += 256) {
        int b = bof[t];
        int s = atomicAdd(&lcur[b], 1);
        srt[s] = pay[t];
        sb[s]  = (unsigned short)b;
    }
    __syncthreads();

    for (int s = tid; s < n; s += 256) {
        int b = sb[s];
        int pos = gbase[b] + (s - lstart[b]);
        if (pos < BINCAP)
            binreg[(size_t)b * BINCAP + pos] = srt[s];
    }
}

// ---------------- level 2: bin segment -> bucket partition ----------------
// writes fused payload = src(0-19) | r(20-22) | g(23-26) into sedge[bucket*CAP]
__global__ __launch_bounds__(256) void refine(
    const unsigned int* __restrict__ binreg, const int* __restrict__ gcur,
    int* __restrict__ bcnt, unsigned int* __restrict__ sedge)
{
    __shared__ unsigned pay[CHUNK];
    __shared__ unsigned short bof[CHUNK];
    __shared__ unsigned srt[CHUNK];
    __shared__ unsigned short sb[CHUNK];
    __shared__ int hist[64], lstart[64], lcur[64], gbase[64];
    __shared__ int scanbuf[64];

    const int tid = threadIdx.x;
    const int bin = blockIdx.x / SEGS;
    const int seg = blockIdx.x % SEGS;
    const int nbin = min(gcur[bin], BINCAP);
    const int s0 = seg * CHUNK;
    if (s0 >= nbin) return;                 // uniform per block
    const int n = min(CHUNK, nbin - s0);

    for (int t = tid; t < 64; t += 256) hist[t] = 0;
    __syncthreads();

    for (int t = tid; t < n; t += 256) {
        unsigned p = binreg[(size_t)bin * BINCAP + s0 + t];
        int bb = (p >> 24) & 63;            // (dst&1023)>>4
        pay[t] = p;
        bof[t] = (unsigned short)bb;
        atomicAdd(&hist[bb], 1);
    }
    __syncthreads();

    if (tid < 64) scanbuf[tid] = hist[tid];
    __syncthreads();
    for (int d = 1; d < 64; d <<= 1) {
        int v = 0;
        if (tid < 64 && tid >= d) v = scanbuf[tid - d];
        __syncthreads();
        if (tid < 64) scanbuf[tid] += v;
        __syncthreads();
    }
    if (tid < 64) {
        int h = hist[tid];
        int excl = scanbuf[tid] - h;
        lstart[tid] = excl;
        lcur[tid]   = excl;
        int bucket = bin * 64 + tid;
        gbase[tid] = (h > 0 && bucket < NBK) ? atomicAdd(&bcnt[bucket], h) : 0;
    }
    __syncthreads();

    for (int t = tid; t < n; t += 256) {
        int b = bof[t];
        int s = atomicAdd(&lcur[b], 1);
        srt[s] = pay[t];
        sb[s]  = (unsigned short)b;
    }
    __syncthreads();

    for (int s = tid; s < n; s += 256) {
        int bb = sb[s];
        unsigned p = srt[s];
        unsigned src = p & 0x1FFFF;
        unsigned r   = (p >> 17) & 7;
        unsigned g   = (p >> 20) & 15;
        int bucket = bin * 64 + bb;
        int pos = gbase[bb] + (s - lstart[bb]);
        if (pos < CAP)
            sedge[(size_t)bucket * CAP + pos] = src | (r << 20) | (g << 23);
    }
}

// ---------------- weight pack: B[K,64] fp32 -> fp16 fragments ----------------
template <int CIN>
__global__ __launch_bounds__(256) void pack_B(
    const float* __restrict__ Wrel,   // [R*CIN, 64]
    const float* __restrict__ Wroot,  // [CIN, 64]
    unsigned short* __restrict__ Bp)
{
    constexpr int K = 9 * CIN, KS = K / 32;
    int idx = blockIdx.x * 256 + threadIdx.x;
    if (idx >= 4 * KS * 64) return;
    int l = idx & 63;
    int rest = idx >> 6;
    int s = rest % KS;
    int t = rest / KS;
    int kb = s * 32 + (l >> 4) * 8;
    int col = t * 16 + (l & 15);
    unsigned short* dst = &Bp[(size_t)idx * 8];
#pragma unroll
    for (int j = 0; j < 8; ++j) {
        int k = kb + j;
        float w = (k < CIN) ? Wroot[k * 64 + col]
                            : Wrel[(size_t)(k - CIN) * 64 + col];
        dst[j] = f2h(w);
    }
}

// ---------------- fold BN into scale/shift ----------------
__global__ __launch_bounds__(64) void prep_scales(
    const float* g1, const float* b1, const float* m1, const float* v1,
    float* sc1, float* sh1,
    const float* g2, const float* b2, const float* m2, const float* v2,
    float* sc2, float* sh2)
{
    int o = threadIdx.x;
    float s1 = g1[o] / sqrtf(v1[o] + EPS);
    sc1[o] = s1;
    sh1[o] = b1[o] - m1[o] * s1;
    float s2 = g2[o] / sqrtf(v2[o] + EPS);
    sc2[o] = s2;
    sh2[o] = b2[o] - m2[o] * s2;
}

// ---------------- fused: LDS sort + batched gather (run-length mean) + MFMA ----
template <int CIN, bool APPLY_RELU, bool OUT_F16>
__global__ __launch_bounds__(256) void fused_layer(
    const unsigned short* __restrict__ x,   // [N, CIN] fp16
    const unsigned int* __restrict__ sedge, // [NBK*CAP] bucketed edges
    const int* __restrict__ bcnt,           // [NBK] bucket counts
    const unsigned short* __restrict__ Bp,  // packed fp16 fragments
    const float* __restrict__ bias,         // [64]
    const float* __restrict__ scale, const float* __restrict__ shift,
    void* __restrict__ outv)                // [N,64] fp16 or fp32
{
    constexpr int NB  = 16;            // nodes per block (= MFMA M)
    constexpr int K   = 9 * CIN;       // 288 or 576
    constexpr int KS  = K / 32;        // MFMA K-steps
    constexpr int Kp  = K + 8;         // padded row stride (shorts)
    constexpr int VEC = CIN / 16;      // channels per lane: 2 or 4

    __shared__ unsigned short As[NB][Kp];
    __shared__ unsigned int   raw[CAP];
    __shared__ unsigned int   srt[CAP];
    __shared__ int cnt128[128];
    __shared__ int segoff[129];
    __shared__ int cur[128];

    const int node0 = blockIdx.x * NB;
    const int tid = threadIdx.x;
    const int nloc = min(bcnt[blockIdx.x], CAP);

    // ---- phase 0a: zero sort counters + copy root rows + zero agg region ----
    if (tid < 128) cnt128[tid] = 0;
    for (int t = tid; t < NB * (CIN / 4); t += 256) {
        int g = t / (CIN / 4), q = (t % (CIN / 4)) * 4;
        *reinterpret_cast<uint2*>(&As[g][q]) =
            *reinterpret_cast<const uint2*>(&x[(size_t)(node0 + g) * CIN + q]);
    }
    {
        uint4 z = {0u, 0u, 0u, 0u};
        for (int t = tid; t < NB * CIN; t += 256) {
            int g = t / CIN, q = (t % CIN) * 8;
            *reinterpret_cast<uint4*>(&As[g][CIN + q]) = z;
        }
    }
    __syncthreads();

    // ---- phase 0b: stage edges + count per (g,r) key ----
    for (int t = tid; t < nloc; t += 256) {
        unsigned se = sedge[(size_t)blockIdx.x * CAP + t];
        raw[t] = se;
        atomicAdd(&cnt128[(se >> 20) & 127], 1);
    }
    __syncthreads();

    // ---- phase 0c: scan 128 counters (Hillis-Steele, in place) ----
    for (int d = 1; d < 128; d <<= 1) {
        int v = 0;
        if (tid < 128 && tid >= d) v = cnt128[tid - d];
        __syncthreads();
        if (tid < 128) cnt128[tid] += v;
        __syncthreads();
    }
    if (tid < 128) segoff[tid + 1] = cnt128[tid];
    if (tid == 0) segoff[0] = 0;
    __syncthreads();
    if (tid < 128) cur[tid] = segoff[tid];
    __syncthreads();

    // ---- phase 0d: place into sorted order ----
    for (int t = tid; t < nloc; t += 256) {
        unsigned se = raw[t];
        int k = (se >> 20) & 127;
        int slot = atomicAdd(&cur[k], 1);
        srt[slot] = se;
    }
    __syncthreads();

    // ---- phase 1: per-node span walk, 4-batched gathers, run-length mean ----
    {
        const int lx = tid & 15;          // 16 lanes per node
        const int g  = tid >> 4;          // node slot 0..15
        const int c0 = lx * VEC;
        const int s = segoff[g * 8];
        const int e = segoff[g * 8 + 8];

        float a0 = 0.f, a1 = 0.f, a2 = 0.f, a3 = 0.f;
        int cur_r = -1, cnt = 0;

        auto flushrun = [&]() {
            if (cnt > 0) {
                float inv = 1.0f / (float)cnt;
                if constexpr (VEC == 4) {
                    uint2 pk;
                    pk.x = (unsigned)f2h(a0 * inv) | ((unsigned)f2h(a1 * inv) << 16);
                    pk.y = (unsigned)f2h(a2 * inv) | ((unsigned)f2h(a3 * inv) << 16);
                    *reinterpret_cast<uint2*>(&As[g][CIN + cur_r * CIN + c0]) = pk;
                } else {
                    unsigned pk = (unsigned)f2h(a0 * inv) |
                                  ((unsigned)f2h(a1 * inv) << 16);
                    *reinterpret_cast<unsigned*>(&As[g][CIN + cur_r * CIN + c0]) = pk;
                }
                a0 = a1 = a2 = a3 = 0.f;
            }
        };
        auto proc = [&](unsigned se, uint2 xv) {
            int r = (int)((se >> 20) & 7);
            if (r != cur_r) { flushrun(); cur_r = r; cnt = 0; }
            a0 += h2f(xv.x & 0xffff);
            a1 += h2f(xv.x >> 16);
            if constexpr (VEC == 4) {
                a2 += h2f(xv.y & 0xffff);
                a3 += h2f(xv.y >> 16);
            }
            ++cnt;
        };
        auto loadx = [&](unsigned se) -> uint2 {
            size_t base = (size_t)(se & 0xFFFFF) * CIN + c0;
            if constexpr (VEC == 4)
                return *reinterpret_cast<const uint2*>(&x[base]);
            else {
                uint2 r2; r2.x = *reinterpret_cast<const unsigned*>(&x[base]); r2.y = 0u;
                return r2;
            }
        };

        int j = s;
        for (; j + 4 <= e; j += 4) {
            unsigned se0 = srt[j],     se1 = srt[j + 1];
            unsigned se2 = srt[j + 2], se3 = srt[j + 3];
            uint2 x0v = loadx(se0);
            uint2 x1v = loadx(se1);
            uint2 x2v = loadx(se2);
            uint2 x3v = loadx(se3);
            proc(se0, x0v); proc(se1, x1v); proc(se2, x2v); proc(se3, x3v);
        }
        for (; j < e; ++j) {
            unsigned se0 = srt[j];
            proc(se0, loadx(se0));
        }
        flushrun();
    }
    __syncthreads();

    // ---- phase 2: [16 x K] * [K x 64] via mfma_f32_16x16x32_f16 ----
    const int lane = tid & 63, wave = tid >> 6;   // wave owns 16-col N-tile
    const int arow = lane & 15;
    const int kb   = (lane >> 4) * 8;
    f32x4 acc = {0.f, 0.f, 0.f, 0.f};
    const unsigned short* a_ptr = &As[arow][kb];
    const unsigned short* b_ptr = &Bp[((size_t)(wave * KS) * 64 + lane) * 8];
#pragma unroll
    for (int ks = 0; ks < KS; ++ks) {
        half8 a = *reinterpret_cast<const half8*>(a_ptr + ks * 32);
        half8 b = *reinterpret_cast<const half8*>(b_ptr + (size_t)ks * 64 * 8);
        acc = __builtin_amdgcn_mfma_f32_16x16x32_f16(a, b, acc, 0, 0, 0);
    }

    // ---- epilogue: bias, (relu), BN; C layout: col=lane&15, row=(lane>>4)*4+r
    const int o = wave * 16 + (lane & 15);
    const float sc = scale[o], sh = shift[o], bi = bias[o];
#pragma unroll
    for (int r = 0; r < 4; ++r) {
        int nrow = (lane >> 4) * 4 + r;
        float t = acc[r] + bi;
        if (APPLY_RELU) t = fmaxf(t, 0.0f);
        t = t * sc + sh;
        size_t oidx = (size_t)(node0 + nrow) * 64 + o;
        if (OUT_F16) ((unsigned short*)outv)[oidx] = f2h(t);
        else         ((float*)outv)[oidx] = t;
    }
}

extern "C" void kernel_launch(void* const* d_in, const int* in_sizes, int n_in,
                              void* d_out, int out_size, void* d_ws, size_t ws_size,
                              hipStream_t stream)
{
    const int*   n_id   = (const int*)d_in[0];
    const int*   ei     = (const int*)d_in[1];   // [2, NE]
    const int*   et     = (const int*)d_in[2];   // [NE]
    const float* emb    = (const float*)d_in[3];
    const float* W1     = (const float*)d_in[4];
    const float* root1  = (const float*)d_in[5];
    const float* b1     = (const float*)d_in[6];
    const float* W2     = (const float*)d_in[7];
    const float* root2  = (const float*)d_in[8];
    const float* b2     = (const float*)d_in[9];
    const float* bn32_g = (const float*)d_in[10];
    const float* bn32_b = (const float*)d_in[11];
    const float* bn32_m = (const float*)d_in[12];
    const float* bn32_v = (const float*)d_in[13];
    const float* bn64_g = (const float*)d_in[14];
    const float* bn64_b = (const float*)d_in[15];
    const float* bn64_m = (const float*)d_in[16];
    const float* bn64_v = (const float*)d_in[17];
    const float* bnb_g  = (const float*)d_in[18];
    const float* bnb_b  = (const float*)d_in[19];
    const float* bnb_m  = (const float*)d_in[20];
    const float* bnb_v  = (const float*)d_in[21];
    float* out = (float*)d_out;

    // workspace layout (all chunks 16B-aligned)
    char* p = (char*)d_ws;
    int* gcur = (int*)p;                       p += (size_t)((NBIN + 3) & ~3) * 4;
    int* bcnt = (int*)p;                       p += (size_t)((NBK + 3) & ~3) * 4;
    unsigned int* binreg = (unsigned int*)p;   p += (size_t)NBIN * BINCAP * 4;
    unsigned int* sedge  = (unsigned int*)p;   p += (size_t)NBK * CAP * 4;
    unsigned short* x0  = (unsigned short*)p;  p += (size_t)NN * 32 * 2;
    unsigned short* h1  = (unsigned short*)p;  p += (size_t)NN * 64 * 2;
    unsigned short* Bp1 = (unsigned short*)p;  p += 4 * 9  * 64 * 8 * 2;
    unsigned short* Bp2 = (unsigned short*)p;  p += 4 * 18 * 64 * 8 * 2;
    float* sc1 = (float*)p;           p += 64 * 4;
    float* sh1 = (float*)p;           p += 64 * 4;
    float* sc2 = (float*)p;           p += 64 * 4;
    float* sh2 = (float*)p;           p += 64 * 4;

    // ---- two-level partition of edges (shared by both layers) ----
    hipMemsetAsync(gcur, 0, ((size_t)((NBIN + 3) & ~3) + (NBK + 3 & ~3)) * 4,
                   stream);   // zeroes gcur + bcnt (adjacent)
    binner<<<NCHUNK, 256, 0, stream>>>(ei, et, gcur, binreg);
    refine<<<NBIN * SEGS, 256, 0, stream>>>(binreg, gcur, bcnt, sedge);

    // ---- weight/bn prep ----
    prep_scales<<<1, 64, 0, stream>>>(bn64_g, bn64_b, bn64_m, bn64_v, sc1, sh1,
                                      bnb_g, bnb_b, bnb_m, bnb_v, sc2, sh2);
    pack_B<32><<<(4 * 9 * 64 + 255) / 256, 256, 0, stream>>>(W1, root1, Bp1);
    pack_B<64><<<(4 * 18 * 64 + 255) / 256, 256, 0, stream>>>(W2, root2, Bp2);

    // ---- layer 1 ----
    compute_x0<<<(NN * 16 + 255) / 256, 256, 0, stream>>>(
        n_id, emb, bn32_g, bn32_b, bn32_m, bn32_v, (unsigned int*)x0);
    fused_layer<32, true, true><<<NBK, 256, 0, stream>>>(
        x0, sedge, bcnt, Bp1, b1, sc1, sh1, h1);

    // ---- layer 2 ----
    fused_layer<64, false, false><<<NBK, 256, 0, stream>>>(
        h1, sedge, bcnt, Bp2, b2, sc2, sh2, out);
}

// Round 10
// 158.328 us; speedup vs baseline: 1.4198x; 1.0134x over previous
//
#include <hip/hip_runtime.h>

#define EPS 1e-5f
constexpr int NN  = 100000;   // nodes
constexpr int NE  = 1600000;  // edges
constexpr int R   = 8;
constexpr int NBK = NN / 16;  // 6250 dst-buckets (one per fused block)
constexpr int CAP = 512;      // bucket capacity (mean 256, sd 16)
constexpr int CHUNK  = 2048;  // edges per binner chunk
constexpr int NCHUNK = (NE + CHUNK - 1) / CHUNK;  // 782
constexpr int NBIN   = 98;    // coarse bins of 1024 nodes (64 buckets each)
constexpr int SEGS   = 9;     // refine segments per bin
constexpr int BINCAP = SEGS * CHUNK;  // 18432 (mean 16384, +16 sigma)

typedef _Float16 half8 __attribute__((ext_vector_type(8)));
typedef _Float16 h2    __attribute__((ext_vector_type(2)));
typedef float f32x4 __attribute__((ext_vector_type(4)));

static __device__ inline unsigned short f2h(float f) {
    _Float16 h = (_Float16)f;
    return __builtin_bit_cast(unsigned short, h);
}

// ---------------- x0 = bn32(emb[n_id]) -> fp16 ----------------
__global__ __launch_bounds__(256) void compute_x0(
    const int* __restrict__ n_id, const float* __restrict__ emb,
    const float* __restrict__ g, const float* __restrict__ b,
    const float* __restrict__ m, const float* __restrict__ v,
    unsigned int* __restrict__ x0)   // [NN*16] uints = [NN,32] fp16
{
    int idx = blockIdx.x * 256 + threadIdx.x;
    if (idx >= NN * 16) return;
    int i = idx >> 4, c = (idx & 15) * 2;
    int nid = n_id[i];
    float2 e = *reinterpret_cast<const float2*>(&emb[nid * 32 + c]);
    float s0 = g[c]     / sqrtf(v[c]     + EPS);
    float s1 = g[c + 1] / sqrtf(v[c + 1] + EPS);
    float y0 = (e.x - m[c])     * s0 + b[c];
    float y1 = (e.y - m[c + 1]) * s1 + b[c + 1];
    x0[idx] = (unsigned int)f2h(y0) | ((unsigned int)f2h(y1) << 16);
}

// ---------------- level 1: chunk -> coarse-bin partition (coalesced runs) ----
// payload2 = src(0-16) | r(17-19) | (dst&1023)(20-29)
__global__ __launch_bounds__(256) void binner(
    const int* __restrict__ ei, const int* __restrict__ et,
    int* __restrict__ gcur, unsigned int* __restrict__ binreg)
{
    __shared__ unsigned pay[CHUNK];
    __shared__ unsigned short bof[CHUNK];
    __shared__ unsigned srt[CHUNK];
    __shared__ unsigned short sb[CHUNK];
    __shared__ int hist[NBIN], lstart[NBIN], lcur[NBIN], gbase[NBIN];
    __shared__ int scanbuf[NBIN];

    const int tid = threadIdx.x;
    const int base = blockIdx.x * CHUNK;
    const int n = min(CHUNK, NE - base);

    for (int t = tid; t < NBIN; t += 256) hist[t] = 0;
    __syncthreads();

    for (int t = tid; t < n; t += 256) {
        int e = base + t;
        int dst = ei[NE + e];
        int bin = dst >> 10;
        pay[t] = (unsigned)ei[e] | ((unsigned)et[e] << 17) |
                 ((unsigned)(dst & 1023) << 20);
        bof[t] = (unsigned short)bin;
        atomicAdd(&hist[bin], 1);
    }
    __syncthreads();

    if (tid < NBIN) scanbuf[tid] = hist[tid];
    __syncthreads();
    for (int d = 1; d < NBIN; d <<= 1) {
        int v = 0;
        if (tid < NBIN && tid >= d) v = scanbuf[tid - d];
        __syncthreads();
        if (tid < NBIN) scanbuf[tid] += v;
        __syncthreads();
    }
    if (tid < NBIN) {
        int h = hist[tid];
        int excl = scanbuf[tid] - h;
        lstart[tid] = excl;
        lcur[tid]   = excl;
        gbase[tid]  = (h > 0) ? atomicAdd(&gcur[tid], h) : 0;
    }
    __syncthreads();

    for (int t = tid; t < n; t += 256) {
        int b = bof[t];
        int s = atomicAdd(&lcur[b], 1);
        srt[s] = pay[t];
        sb[s]  = (unsigned short)b;
    }
    __syncthreads();

    for (int s = tid; s < n; s += 256) {
        int b = sb[s];
        int pos = gbase[b] + (s - lstart[b]);
        if (pos < BINCAP)
            binreg[(size_t)b * BINCAP + pos] = srt[s];
    }
}

// ---------------- level 2: bin segment -> bucket partition ----------------
// writes fused payload = src(0-19) | r(20-22) | g(23-26) into sedge[bucket*CAP]
__global__ __launch_bounds__(256) void refine(
    const unsigned int* __restrict__ binreg, const int* __restrict__ gcur,
    int* __restrict__ bcnt, unsigned int* __restrict__ sedge)
{
    __shared__ unsigned pay[CHUNK];
    __shared__ unsigned short bof[CHUNK];
    __shared__ unsigned srt[CHUNK];
    __shared__ unsigned short sb[CHUNK];
    __shared__ int hist[64], lstart[64], lcur[64], gbase[64];
    __shared__ int scanbuf[64];

    const int tid = threadIdx.x;
    const int bin = blockIdx.x / SEGS;
    const int seg = blockIdx.x % SEGS;
    const int nbin = min(gcur[bin], BINCAP);
    const int s0 = seg * CHUNK;
    if (s0 >= nbin) return;                 // uniform per block
    const int n = min(CHUNK, nbin - s0);

    for (int t = tid; t < 64; t += 256) hist[t] = 0;
    __syncthreads();

    for (int t = tid; t < n; t += 256) {
        unsigned p = binreg[(size_t)bin * BINCAP + s0 + t];
        int bb = (p >> 24) & 63;            // (dst&1023)>>4
        pay[t] = p;
        bof[t] = (unsigned short)bb;
        atomicAdd(&hist[bb], 1);
    }
    __syncthreads();

    if (tid < 64) scanbuf[tid] = hist[tid];
    __syncthreads();
    for (int d = 1; d < 64; d <<= 1) {
        int v = 0;
        if (tid < 64 && tid >= d) v = scanbuf[tid - d];
        __syncthreads();
        if (tid < 64) scanbuf[tid] += v;
        __syncthreads();
    }
    if (tid < 64) {
        int h = hist[tid];
        int excl = scanbuf[tid] - h;
        lstart[tid] = excl;
        lcur[tid]   = excl;
        int bucket = bin * 64 + tid;
        gbase[tid] = (h > 0 && bucket < NBK) ? atomicAdd(&bcnt[bucket], h) : 0;
    }
    __syncthreads();

    for (int t = tid; t < n; t += 256) {
        int b = bof[t];
        int s = atomicAdd(&lcur[b], 1);
        srt[s] = pay[t];
        sb[s]  = (unsigned short)b;
    }
    __syncthreads();

    for (int s = tid; s < n; s += 256) {
        int bb = sb[s];
        unsigned p = srt[s];
        unsigned src = p & 0x1FFFF;
        unsigned r   = (p >> 17) & 7;
        unsigned g   = (p >> 20) & 15;
        int bucket = bin * 64 + bb;
        int pos = gbase[bb] + (s - lstart[bb]);
        if (pos < CAP)
            sedge[(size_t)bucket * CAP + pos] = src | (r << 20) | (g << 23);
    }
}

// ---------------- weight pack: B[K,64] fp32 -> fp16 fragments ----------------
template <int CIN>
__global__ __launch_bounds__(256) void pack_B(
    const float* __restrict__ Wrel,   // [R*CIN, 64]
    const float* __restrict__ Wroot,  // [CIN, 64]
    unsigned short* __restrict__ Bp)
{
    constexpr int K = 9 * CIN, KS = K / 32;
    int idx = blockIdx.x * 256 + threadIdx.x;
    if (idx >= 4 * KS * 64) return;
    int l = idx & 63;
    int rest = idx >> 6;
    int s = rest % KS;
    int t = rest / KS;
    int kb = s * 32 + (l >> 4) * 8;
    int col = t * 16 + (l & 15);
    unsigned short* dst = &Bp[(size_t)idx * 8];
#pragma unroll
    for (int j = 0; j < 8; ++j) {
        int k = kb + j;
        float w = (k < CIN) ? Wroot[k * 64 + col]
                            : Wrel[(size_t)(k - CIN) * 64 + col];
        dst[j] = f2h(w);
    }
}

// ---------------- fold BN into scale/shift ----------------
__global__ __launch_bounds__(64) void prep_scales(
    const float* g1, const float* b1, const float* m1, const float* v1,
    float* sc1, float* sh1,
    const float* g2, const float* b2, const float* m2, const float* v2,
    float* sc2, float* sh2)
{
    int o = threadIdx.x;
    float s1 = g1[o] / sqrtf(v1[o] + EPS);
    sc1[o] = s1;
    sh1[o] = b1[o] - m1[o] * s1;
    float s2 = g2[o] / sqrtf(v2[o] + EPS);
    sc2[o] = s2;
    sh2[o] = b2[o] - m2[o] * s2;
}

// ---------------- fused: LDS sort + batched gather (pk_f16 run mean) + MFMA ----
template <int CIN, bool APPLY_RELU, bool OUT_F16>
__global__ __launch_bounds__(256) void fused_layer(
    const unsigned short* __restrict__ x,   // [N, CIN] fp16
    const unsigned int* __restrict__ sedge, // [NBK*CAP] bucketed edges
    const int* __restrict__ bcnt,           // [NBK] bucket counts
    const unsigned short* __restrict__ Bp,  // packed fp16 fragments
    const float* __restrict__ bias,         // [64]
    const float* __restrict__ scale, const float* __restrict__ shift,
    void* __restrict__ outv)                // [N,64] fp16 or fp32
{
    constexpr int NB  = 16;            // nodes per block (= MFMA M)
    constexpr int K   = 9 * CIN;       // 288 or 576
    constexpr int KS  = K / 32;        // MFMA K-steps
    constexpr int Kp  = K + 8;         // padded row stride (shorts)
    constexpr int VEC = CIN / 16;      // channels per lane: 2 or 4

    __shared__ unsigned short As[NB][Kp];
    __shared__ unsigned int   raw[CAP];
    __shared__ unsigned int   srt[CAP];
    __shared__ int cnt128[128];
    __shared__ int segoff[129];
    __shared__ int cur[128];

    const int node0 = blockIdx.x * NB;
    const int tid = threadIdx.x;
    const int nloc = min(bcnt[blockIdx.x], CAP);

    // ---- phase 0a: zero sort counters + copy root rows + zero agg region ----
    if (tid < 128) cnt128[tid] = 0;
    for (int t = tid; t < NB * (CIN / 4); t += 256) {
        int g = t / (CIN / 4), q = (t % (CIN / 4)) * 4;
        *reinterpret_cast<uint2*>(&As[g][q]) =
            *reinterpret_cast<const uint2*>(&x[(size_t)(node0 + g) * CIN + q]);
    }
    {
        uint4 z = {0u, 0u, 0u, 0u};
        for (int t = tid; t < NB * CIN; t += 256) {
            int g = t / CIN, q = (t % CIN) * 8;
            *reinterpret_cast<uint4*>(&As[g][CIN + q]) = z;
        }
    }
    __syncthreads();

    // ---- phase 0b: stage edges + count per (g,r) key ----
    for (int t = tid; t < nloc; t += 256) {
        unsigned se = sedge[(size_t)blockIdx.x * CAP + t];
        raw[t] = se;
        atomicAdd(&cnt128[(se >> 20) & 127], 1);
    }
    __syncthreads();

    // ---- phase 0c: scan 128 counters (Hillis-Steele, in place) ----
    for (int d = 1; d < 128; d <<= 1) {
        int v = 0;
        if (tid < 128 && tid >= d) v = cnt128[tid - d];
        __syncthreads();
        if (tid < 128) cnt128[tid] += v;
        __syncthreads();
    }
    if (tid < 128) segoff[tid + 1] = cnt128[tid];
    if (tid == 0) segoff[0] = 0;
    __syncthreads();
    if (tid < 128) cur[tid] = segoff[tid];
    __syncthreads();

    // ---- phase 0d: place into sorted order ----
    for (int t = tid; t < nloc; t += 256) {
        unsigned se = raw[t];
        int k = (se >> 20) & 127;
        int slot = atomicAdd(&cur[k], 1);
        srt[slot] = se;
    }
    __syncthreads();

    // ---- phase 1: span walk, 4-batched gathers, packed-fp16 run mean ----
    {
        const int lx = tid & 15;          // 16 lanes per node
        const int g  = tid >> 4;          // node slot 0..15
        const int c0 = lx * VEC;
        const int s = segoff[g * 8];
        const int e = segoff[g * 8 + 8];

        h2 a01 = {(_Float16)0, (_Float16)0};
        h2 a23 = {(_Float16)0, (_Float16)0};
        int cur_r = -1, cnt = 0;

        auto flushrun = [&]() {
            if (cnt > 0) {
                _Float16 ih = (_Float16)(1.0f / (float)cnt);
                h2 iv = {ih, ih};
                if constexpr (VEC == 4) {
                    uint2 pk;
                    pk.x = __builtin_bit_cast(unsigned, (h2)(a01 * iv));
                    pk.y = __builtin_bit_cast(unsigned, (h2)(a23 * iv));
                    *reinterpret_cast<uint2*>(&As[g][CIN + cur_r * CIN + c0]) = pk;
                    a23 = (h2){(_Float16)0, (_Float16)0};
                } else {
                    unsigned pk = __builtin_bit_cast(unsigned, (h2)(a01 * iv));
                    *reinterpret_cast<unsigned*>(&As[g][CIN + cur_r * CIN + c0]) = pk;
                }
                a01 = (h2){(_Float16)0, (_Float16)0};
            }
        };
        auto proc = [&](unsigned se, uint2 xv) {
            int r = (int)((se >> 20) & 7);
            if (r != cur_r) { flushrun(); cur_r = r; cnt = 0; }
            a01 += __builtin_bit_cast(h2, xv.x);
            if constexpr (VEC == 4)
                a23 += __builtin_bit_cast(h2, xv.y);
            ++cnt;
        };
        auto loadx = [&](unsigned se) -> uint2 {
            size_t base = (size_t)(se & 0xFFFFF) * CIN + c0;
            if constexpr (VEC == 4)
                return *reinterpret_cast<const uint2*>(&x[base]);
            else {
                uint2 r2; r2.x = *reinterpret_cast<const unsigned*>(&x[base]); r2.y = 0u;
                return r2;
            }
        };

        int j = s;
        for (; j + 4 <= e; j += 4) {
            unsigned se0 = srt[j],     se1 = srt[j + 1];
            unsigned se2 = srt[j + 2], se3 = srt[j + 3];
            uint2 x0v = loadx(se0);
            uint2 x1v = loadx(se1);
            uint2 x2v = loadx(se2);
            uint2 x3v = loadx(se3);
            proc(se0, x0v); proc(se1, x1v); proc(se2, x2v); proc(se3, x3v);
        }
        for (; j < e; ++j) {
            unsigned se0 = srt[j];
            proc(se0, loadx(se0));
        }
        flushrun();
    }
    __syncthreads();

    // ---- phase 2: [16 x K] * [K x 64] via mfma_f32_16x16x32_f16 ----
    const int lane = tid & 63, wave = tid >> 6;   // wave owns 16-col N-tile
    const int arow = lane & 15;
    const int kb   = (lane >> 4) * 8;
    f32x4 acc = {0.f, 0.f, 0.f, 0.f};
    const unsigned short* a_ptr = &As[arow][kb];
    const unsigned short* b_ptr = &Bp[((size_t)(wave * KS) * 64 + lane) * 8];
#pragma unroll
    for (int ks = 0; ks < KS; ++ks) {
        half8 a = *reinterpret_cast<const half8*>(a_ptr + ks * 32);
        half8 b = *reinterpret_cast<const half8*>(b_ptr + (size_t)ks * 64 * 8);
        acc = __builtin_amdgcn_mfma_f32_16x16x32_f16(a, b, acc, 0, 0, 0);
    }

    // ---- epilogue: bias, (relu), BN; C layout: col=lane&15, row=(lane>>4)*4+r
    const int o = wave * 16 + (lane & 15);
    const float sc = scale[o], sh = shift[o], bi = bias[o];
#pragma unroll
    for (int r = 0; r < 4; ++r) {
        int nrow = (lane >> 4) * 4 + r;
        float t = acc[r] + bi;
        if (APPLY_RELU) t = fmaxf(t, 0.0f);
        t = t * sc + sh;
        size_t oidx = (size_t)(node0 + nrow) * 64 + o;
        if (OUT_F16) ((unsigned short*)outv)[oidx] = f2h(t);
        else         ((float*)outv)[oidx] = t;
    }
}

extern "C" void kernel_launch(void* const* d_in, const int* in_sizes, int n_in,
                              void* d_out, int out_size, void* d_ws, size_t ws_size,
                              hipStream_t stream)
{
    const int*   n_id   = (const int*)d_in[0];
    const int*   ei     = (const int*)d_in[1];   // [2, NE]
    const int*   et     = (const int*)d_in[2];   // [NE]
    const float* emb    = (const float*)d_in[3];
    const float* W1     = (const float*)d_in[4];
    const float* root1  = (const float*)d_in[5];
    const float* b1     = (const float*)d_in[6];
    const float* W2     = (const float*)d_in[7];
    const float* root2  = (const float*)d_in[8];
    const float* b2     = (const float*)d_in[9];
    const float* bn32_g = (const float*)d_in[10];
    const float* bn32_b = (const float*)d_in[11];
    const float* bn32_m = (const float*)d_in[12];
    const float* bn32_v = (const float*)d_in[13];
    const float* bn64_g = (const float*)d_in[14];
    const float* bn64_b = (const float*)d_in[15];
    const float* bn64_m = (const float*)d_in[16];
    const float* bn64_v = (const float*)d_in[17];
    const float* bnb_g  = (const float*)d_in[18];
    const float* bnb_b  = (const float*)d_in[19];
    const float* bnb_m  = (const float*)d_in[20];
    const float* bnb_v  = (const float*)d_in[21];
    float* out = (float*)d_out;

    // workspace layout (all chunks 16B-aligned)
    char* p = (char*)d_ws;
    int* gcur = (int*)p;                       p += (size_t)((NBIN + 3) & ~3) * 4;
    int* bcnt = (int*)p;                       p += (size_t)((NBK + 3) & ~3) * 4;
    unsigned int* binreg = (unsigned int*)p;   p += (size_t)NBIN * BINCAP * 4;
    unsigned int* sedge  = (unsigned int*)p;   p += (size_t)NBK * CAP * 4;
    unsigned short* x0  = (unsigned short*)p;  p += (size_t)NN * 32 * 2;
    unsigned short* h1  = (unsigned short*)p;  p += (size_t)NN * 64 * 2;
    unsigned short* Bp1 = (unsigned short*)p;  p += 4 * 9  * 64 * 8 * 2;
    unsigned short* Bp2 = (unsigned short*)p;  p += 4 * 18 * 64 * 8 * 2;
    float* sc1 = (float*)p;           p += 64 * 4;
    float* sh1 = (float*)p;           p += 64 * 4;
    float* sc2 = (float*)p;           p += 64 * 4;
    float* sh2 = (float*)p;           p += 64 * 4;

    // ---- two-level partition of edges (shared by both layers) ----
    hipMemsetAsync(gcur, 0, ((size_t)((NBIN + 3) & ~3) + (NBK + 3 & ~3)) * 4,
                   stream);   // zeroes gcur + bcnt (adjacent)
    binner<<<NCHUNK, 256, 0, stream>>>(ei, et, gcur, binreg);
    refine<<<NBIN * SEGS, 256, 0, stream>>>(binreg, gcur, bcnt, sedge);

    // ---- weight/bn prep ----
    prep_scales<<<1, 64, 0, stream>>>(bn64_g, bn64_b, bn64_m, bn64_v, sc1, sh1,
                                      bnb_g, bnb_b, bnb_m, bnb_v, sc2, sh2);
    pack_B<32><<<(4 * 9 * 64 + 255) / 256, 256, 0, stream>>>(W1, root1, Bp1);
    pack_B<64><<<(4 * 18 * 64 + 255) / 256, 256, 0, stream>>>(W2, root2, Bp2);

    // ---- layer 1 ----
    compute_x0<<<(NN * 16 + 255) / 256, 256, 0, stream>>>(
        n_id, emb, bn32_g, bn32_b, bn32_m, bn32_v, (unsigned int*)x0);
    fused_layer<32, true, true><<<NBK, 256, 0, stream>>>(
        x0, sedge, bcnt, Bp1, b1, sc1, sh1, h1);

    // ---- layer 2 ----
    fused_layer<64, false, false><<<NBK, 256, 0, stream>>>(
        h1, sedge, bcnt, Bp2, b2, sc2, sh2, out);
}

// Round 11
// 154.491 us; speedup vs baseline: 1.4550x; 1.0248x over previous
//
#include <hip/hip_runtime.h>

#define EPS 1e-5f
constexpr int NN  = 100000;   // nodes
constexpr int NE  = 1600000;  // edges
constexpr int R   = 8;
constexpr int NBK = NN / 16;  // 6250 dst-buckets (one per fused block)
constexpr int CAP = 512;      // bucket capacity (mean 256, sd 16)
constexpr int CHUNK  = 2048;  // edges per binner chunk
constexpr int NCHUNK = (NE + CHUNK - 1) / CHUNK;  // 782
constexpr int NBIN   = 98;    // coarse bins of 1024 nodes (64 buckets each)
constexpr int SEGS   = 9;     // refine segments per bin
constexpr int BINCAP = SEGS * CHUNK;  // 18432 (mean 16384, +16 sigma)

typedef _Float16 half8 __attribute__((ext_vector_type(8)));
typedef _Float16 h2    __attribute__((ext_vector_type(2)));
typedef float f32x4 __attribute__((ext_vector_type(4)));

static __device__ inline unsigned short f2h(float f) {
    _Float16 h = (_Float16)f;
    return __builtin_bit_cast(unsigned short, h);
}

// ---------------- x0 = bn32(emb[n_id]) -> fp16 ----------------
__global__ __launch_bounds__(256) void compute_x0(
    const int* __restrict__ n_id, const float* __restrict__ emb,
    const float* __restrict__ g, const float* __restrict__ b,
    const float* __restrict__ m, const float* __restrict__ v,
    unsigned int* __restrict__ x0)   // [NN*16] uints = [NN,32] fp16
{
    int idx = blockIdx.x * 256 + threadIdx.x;
    if (idx >= NN * 16) return;
    int i = idx >> 4, c = (idx & 15) * 2;
    int nid = n_id[i];
    float2 e = *reinterpret_cast<const float2*>(&emb[nid * 32 + c]);
    float s0 = g[c]     / sqrtf(v[c]     + EPS);
    float s1 = g[c + 1] / sqrtf(v[c + 1] + EPS);
    float y0 = (e.x - m[c])     * s0 + b[c];
    float y1 = (e.y - m[c + 1]) * s1 + b[c + 1];
    x0[idx] = (unsigned int)f2h(y0) | ((unsigned int)f2h(y1) << 16);
}

// ---------------- level 1: chunk -> coarse-bin partition (coalesced runs) ----
// payload2 = src(0-16) | r(17-19) | (dst&1023)(20-29)
__global__ __launch_bounds__(256) void binner(
    const int* __restrict__ ei, const int* __restrict__ et,
    int* __restrict__ gcur, unsigned int* __restrict__ binreg)
{
    __shared__ unsigned pay[CHUNK];
    __shared__ unsigned short bof[CHUNK];
    __shared__ unsigned srt[CHUNK];
    __shared__ unsigned short sb[CHUNK];
    __shared__ int hist[NBIN], lstart[NBIN], lcur[NBIN], gbase[NBIN];
    __shared__ int scanbuf[NBIN];

    const int tid = threadIdx.x;
    const int base = blockIdx.x * CHUNK;
    const int n = min(CHUNK, NE - base);

    for (int t = tid; t < NBIN; t += 256) hist[t] = 0;
    __syncthreads();

    for (int t = tid; t < n; t += 256) {
        int e = base + t;
        int dst = ei[NE + e];
        int bin = dst >> 10;
        pay[t] = (unsigned)ei[e] | ((unsigned)et[e] << 17) |
                 ((unsigned)(dst & 1023) << 20);
        bof[t] = (unsigned short)bin;
        atomicAdd(&hist[bin], 1);
    }
    __syncthreads();

    if (tid < NBIN) scanbuf[tid] = hist[tid];
    __syncthreads();
    for (int d = 1; d < NBIN; d <<= 1) {
        int v = 0;
        if (tid < NBIN && tid >= d) v = scanbuf[tid - d];
        __syncthreads();
        if (tid < NBIN) scanbuf[tid] += v;
        __syncthreads();
    }
    if (tid < NBIN) {
        int h = hist[tid];
        int excl = scanbuf[tid] - h;
        lstart[tid] = excl;
        lcur[tid]   = excl;
        gbase[tid]  = (h > 0) ? atomicAdd(&gcur[tid], h) : 0;
    }
    __syncthreads();

    for (int t = tid; t < n; t += 256) {
        int b = bof[t];
        int s = atomicAdd(&lcur[b], 1);
        srt[s] = pay[t];
        sb[s]  = (unsigned short)b;
    }
    __syncthreads();

    for (int s = tid; s < n; s += 256) {
        int b = sb[s];
        int pos = gbase[b] + (s - lstart[b]);
        if (pos < BINCAP)
            binreg[(size_t)b * BINCAP + pos] = srt[s];
    }
}

// ---------------- level 2: bin segment -> bucket partition ----------------
// writes fused payload = src(0-19) | r(20-22) | g(23-26) into sedge[bucket*CAP]
__global__ __launch_bounds__(256) void refine(
    const unsigned int* __restrict__ binreg, const int* __restrict__ gcur,
    int* __restrict__ bcnt, unsigned int* __restrict__ sedge)
{
    __shared__ unsigned pay[CHUNK];
    __shared__ unsigned short bof[CHUNK];
    __shared__ unsigned srt[CHUNK];
    __shared__ unsigned short sb[CHUNK];
    __shared__ int hist[64], lstart[64], lcur[64], gbase[64];
    __shared__ int scanbuf[64];

    const int tid = threadIdx.x;
    const int bin = blockIdx.x / SEGS;
    const int seg = blockIdx.x % SEGS;
    const int nbin = min(gcur[bin], BINCAP);
    const int s0 = seg * CHUNK;
    if (s0 >= nbin) return;                 // uniform per block
    const int n = min(CHUNK, nbin - s0);

    for (int t = tid; t < 64; t += 256) hist[t] = 0;
    __syncthreads();

    for (int t = tid; t < n; t += 256) {
        unsigned p = binreg[(size_t)bin * BINCAP + s0 + t];
        int bb = (p >> 24) & 63;            // (dst&1023)>>4
        pay[t] = p;
        bof[t] = (unsigned short)bb;
        atomicAdd(&hist[bb], 1);
    }
    __syncthreads();

    if (tid < 64) scanbuf[tid] = hist[tid];
    __syncthreads();
    for (int d = 1; d < 64; d <<= 1) {
        int v = 0;
        if (tid < 64 && tid >= d) v = scanbuf[tid - d];
        __syncthreads();
        if (tid < 64) scanbuf[tid] += v;
        __syncthreads();
    }
    if (tid < 64) {
        int h = hist[tid];
        int excl = scanbuf[tid] - h;
        lstart[tid] = excl;
        lcur[tid]   = excl;
        int bucket = bin * 64 + tid;
        gbase[tid] = (h > 0 && bucket < NBK) ? atomicAdd(&bcnt[bucket], h) : 0;
    }
    __syncthreads();

    for (int t = tid; t < n; t += 256) {
        int b = bof[t];
        int s = atomicAdd(&lcur[b], 1);
        srt[s] = pay[t];
        sb[s]  = (unsigned short)b;
    }
    __syncthreads();

    for (int s = tid; s < n; s += 256) {
        int bb = sb[s];
        unsigned p = srt[s];
        unsigned src = p & 0x1FFFF;
        unsigned r   = (p >> 17) & 7;
        unsigned g   = (p >> 20) & 15;
        int bucket = bin * 64 + bb;
        int pos = gbase[bb] + (s - lstart[bb]);
        if (pos < CAP)
            sedge[(size_t)bucket * CAP + pos] = src | (r << 20) | (g << 23);
    }
}

// ---------------- weight pack: B[K,64] fp32 -> fp16 fragments ----------------
template <int CIN>
__global__ __launch_bounds__(256) void pack_B(
    const float* __restrict__ Wrel,   // [R*CIN, 64]
    const float* __restrict__ Wroot,  // [CIN, 64]
    unsigned short* __restrict__ Bp)
{
    constexpr int K = 9 * CIN, KS = K / 32;
    int idx = blockIdx.x * 256 + threadIdx.x;
    if (idx >= 4 * KS * 64) return;
    int l = idx & 63;
    int rest = idx >> 6;
    int s = rest % KS;
    int t = rest / KS;
    int kb = s * 32 + (l >> 4) * 8;
    int col = t * 16 + (l & 15);
    unsigned short* dst = &Bp[(size_t)idx * 8];
#pragma unroll
    for (int j = 0; j < 8; ++j) {
        int k = kb + j;
        float w = (k < CIN) ? Wroot[k * 64 + col]
                            : Wrel[(size_t)(k - CIN) * 64 + col];
        dst[j] = f2h(w);
    }
}

// ---------------- fold BN into scale/shift ----------------
__global__ __launch_bounds__(64) void prep_scales(
    const float* g1, const float* b1, const float* m1, const float* v1,
    float* sc1, float* sh1,
    const float* g2, const float* b2, const float* m2, const float* v2,
    float* sc2, float* sh2)
{
    int o = threadIdx.x;
    float s1 = g1[o] / sqrtf(v1[o] + EPS);
    sc1[o] = s1;
    sh1[o] = b1[o] - m1[o] * s1;
    float s2 = g2[o] / sqrtf(v2[o] + EPS);
    sc2[o] = s2;
    sh2[o] = b2[o] - m2[o] * s2;
}

// ---------------- fused: LDS sort + split-span gather (pk_f16 run mean) + MFMA
template <int CIN, bool APPLY_RELU, bool OUT_F16>
__global__ __launch_bounds__(256) void fused_layer(
    const unsigned short* __restrict__ x,   // [N, CIN] fp16
    const unsigned int* __restrict__ sedge, // [NBK*CAP] bucketed edges
    const int* __restrict__ bcnt,           // [NBK] bucket counts
    const unsigned short* __restrict__ Bp,  // packed fp16 fragments
    const float* __restrict__ bias,         // [64]
    const float* __restrict__ scale, const float* __restrict__ shift,
    void* __restrict__ outv)                // [N,64] fp16 or fp32
{
    constexpr int NB  = 16;            // nodes per block (= MFMA M)
    constexpr int K   = 9 * CIN;       // 288 or 576
    constexpr int KS  = K / 32;        // MFMA K-steps
    constexpr int Kp  = K + 8;         // padded row stride (shorts)

    __shared__ unsigned short As[NB][Kp];
    __shared__ unsigned int   srt[CAP];
    __shared__ int cnt128[128];
    __shared__ int segoff[129];
    __shared__ int cur[128];

    const int node0 = blockIdx.x * NB;
    const int tid = threadIdx.x;
    const int nloc = min(bcnt[blockIdx.x], CAP);
    const unsigned int* sedge_b = &sedge[(size_t)blockIdx.x * CAP];

    // ---- phase 0a: zero sort counters + copy root rows + zero agg region ----
    if (tid < 128) cnt128[tid] = 0;
    for (int t = tid; t < NB * (CIN / 4); t += 256) {
        int g = t / (CIN / 4), q = (t % (CIN / 4)) * 4;
        *reinterpret_cast<uint2*>(&As[g][q]) =
            *reinterpret_cast<const uint2*>(&x[(size_t)(node0 + g) * CIN + q]);
    }
    {
        uint4 z = {0u, 0u, 0u, 0u};
        for (int t = tid; t < NB * CIN; t += 256) {
            int g = t / CIN, q = (t % CIN) * 8;
            *reinterpret_cast<uint4*>(&As[g][CIN + q]) = z;
        }
    }
    __syncthreads();

    // ---- phase 0b: count per (g,r) key (sedge read stays L2-hot) ----
    for (int t = tid; t < nloc; t += 256)
        atomicAdd(&cnt128[(sedge_b[t] >> 20) & 127], 1);
    __syncthreads();

    // ---- phase 0c: scan 128 counters (Hillis-Steele, in place) ----
    for (int d = 1; d < 128; d <<= 1) {
        int v = 0;
        if (tid < 128 && tid >= d) v = cnt128[tid - d];
        __syncthreads();
        if (tid < 128) cnt128[tid] += v;
        __syncthreads();
    }
    if (tid < 128) segoff[tid + 1] = cnt128[tid];
    if (tid == 0) segoff[0] = 0;
    __syncthreads();
    if (tid < 128) cur[tid] = segoff[tid];
    __syncthreads();

    // ---- phase 0d: place into sorted order (re-read sedge, L2-hit) ----
    for (int t = tid; t < nloc; t += 256) {
        unsigned se = sedge_b[t];
        int k = (se >> 20) & 127;
        int slot = atomicAdd(&cur[k], 1);
        srt[slot] = se;
    }
    __syncthreads();

    // ---- phase 1: half-span walk, 8-lane sub-groups, packed-fp16 run mean ----
    {
        const int sg   = tid >> 3;        // 32 sub-groups, 2 per node
        const int ln   = tid & 7;         // 8 lanes per sub-group
        const int g    = sg >> 1;
        const int half = sg & 1;
        const int c0   = ln * (CIN / 8);  // 8 ch/lane (CIN=64), 4 ch/lane (CIN=32)
        const int s = segoff[g * 8];
        const int e = segoff[g * 8 + 8];

        // split span at run boundary so each (g,r) bucket lives in one half
        int mm = s + ((e - s + 1) >> 1);
        if (mm > s && mm < e) {
            int rprev = (srt[mm - 1] >> 20) & 7;
            while (mm < e && (((srt[mm] >> 20) & 7) == rprev)) ++mm;
        }
        const int js = half ? mm : s;
        const int je = half ? e  : mm;

        h2 a0 = {(_Float16)0, (_Float16)0};
        h2 a1 = {(_Float16)0, (_Float16)0};
        h2 a2 = {(_Float16)0, (_Float16)0};
        h2 a3 = {(_Float16)0, (_Float16)0};
        int cur_r = -1, cnt = 0;

        auto flushrun = [&]() {
            if (cnt > 0) {
                _Float16 ih = (_Float16)(1.0f / (float)cnt);
                h2 iv = {ih, ih};
                if constexpr (CIN == 64) {
                    uint4 pk;
                    pk.x = __builtin_bit_cast(unsigned, (h2)(a0 * iv));
                    pk.y = __builtin_bit_cast(unsigned, (h2)(a1 * iv));
                    pk.z = __builtin_bit_cast(unsigned, (h2)(a2 * iv));
                    pk.w = __builtin_bit_cast(unsigned, (h2)(a3 * iv));
                    *reinterpret_cast<uint4*>(&As[g][CIN + cur_r * CIN + c0]) = pk;
                    a2 = (h2){(_Float16)0, (_Float16)0};
                    a3 = (h2){(_Float16)0, (_Float16)0};
                } else {
                    uint2 pk;
                    pk.x = __builtin_bit_cast(unsigned, (h2)(a0 * iv));
                    pk.y = __builtin_bit_cast(unsigned, (h2)(a1 * iv));
                    *reinterpret_cast<uint2*>(&As[g][CIN + cur_r * CIN + c0]) = pk;
                    a1 = (h2){(_Float16)0, (_Float16)0};
                }
                a0 = (h2){(_Float16)0, (_Float16)0};
                if constexpr (CIN == 64)
                    a1 = (h2){(_Float16)0, (_Float16)0};
            }
        };
        auto proc = [&](unsigned se, uint4 xv) {
            int r = (int)((se >> 20) & 7);
            if (r != cur_r) { flushrun(); cur_r = r; cnt = 0; }
            a0 += __builtin_bit_cast(h2, xv.x);
            a1 += __builtin_bit_cast(h2, xv.y);
            if constexpr (CIN == 64) {
                a2 += __builtin_bit_cast(h2, xv.z);
                a3 += __builtin_bit_cast(h2, xv.w);
            }
            ++cnt;
        };
        auto loadx = [&](unsigned se) -> uint4 {
            size_t base = (size_t)(se & 0xFFFFF) * CIN + c0;
            if constexpr (CIN == 64)
                return *reinterpret_cast<const uint4*>(&x[base]);
            else {
                uint2 t2 = *reinterpret_cast<const uint2*>(&x[base]);
                return make_uint4(t2.x, t2.y, 0u, 0u);
            }
        };

        int j = js;
        for (; j + 4 <= je; j += 4) {
            unsigned se0 = srt[j],     se1 = srt[j + 1];
            unsigned se2 = srt[j + 2], se3 = srt[j + 3];
            uint4 v0 = loadx(se0);
            uint4 v1 = loadx(se1);
            uint4 v2 = loadx(se2);
            uint4 v3 = loadx(se3);
            proc(se0, v0); proc(se1, v1); proc(se2, v2); proc(se3, v3);
        }
        for (; j < je; ++j) {
            unsigned se0 = srt[j];
            proc(se0, loadx(se0));
        }
        flushrun();
    }
    __syncthreads();

    // ---- phase 2: [16 x K] * [K x 64] via mfma_f32_16x16x32_f16 ----
    const int lane = tid & 63, wave = tid >> 6;   // wave owns 16-col N-tile
    const int arow = lane & 15;
    const int kb   = (lane >> 4) * 8;
    f32x4 acc = {0.f, 0.f, 0.f, 0.f};
    const unsigned short* a_ptr = &As[arow][kb];
    const unsigned short* b_ptr = &Bp[((size_t)(wave * KS) * 64 + lane) * 8];
#pragma unroll
    for (int ks = 0; ks < KS; ++ks) {
        half8 a = *reinterpret_cast<const half8*>(a_ptr + ks * 32);
        half8 b = *reinterpret_cast<const half8*>(b_ptr + (size_t)ks * 64 * 8);
        acc = __builtin_amdgcn_mfma_f32_16x16x32_f16(a, b, acc, 0, 0, 0);
    }

    // ---- epilogue: bias, (relu), BN; C layout: col=lane&15, row=(lane>>4)*4+r
    const int o = wave * 16 + (lane & 15);
    const float sc = scale[o], sh = shift[o], bi = bias[o];
#pragma unroll
    for (int r = 0; r < 4; ++r) {
        int nrow = (lane >> 4) * 4 + r;
        float t = acc[r] + bi;
        if (APPLY_RELU) t = fmaxf(t, 0.0f);
        t = t * sc + sh;
        size_t oidx = (size_t)(node0 + nrow) * 64 + o;
        if (OUT_F16) ((unsigned short*)outv)[oidx] = f2h(t);
        else         ((float*)outv)[oidx] = t;
    }
}

extern "C" void kernel_launch(void* const* d_in, const int* in_sizes, int n_in,
                              void* d_out, int out_size, void* d_ws, size_t ws_size,
                              hipStream_t stream)
{
    const int*   n_id   = (const int*)d_in[0];
    const int*   ei     = (const int*)d_in[1];   // [2, NE]
    const int*   et     = (const int*)d_in[2];   // [NE]
    const float* emb    = (const float*)d_in[3];
    const float* W1     = (const float*)d_in[4];
    const float* root1  = (const float*)d_in[5];
    const float* b1     = (const float*)d_in[6];
    const float* W2     = (const float*)d_in[7];
    const float* root2  = (const float*)d_in[8];
    const float* b2     = (const float*)d_in[9];
    const float* bn32_g = (const float*)d_in[10];
    const float* bn32_b = (const float*)d_in[11];
    const float* bn32_m = (const float*)d_in[12];
    const float* bn32_v = (const float*)d_in[13];
    const float* bn64_g = (const float*)d_in[14];
    const float* bn64_b = (const float*)d_in[15];
    const float* bn64_m = (const float*)d_in[16];
    const float* bn64_v = (const float*)d_in[17];
    const float* bnb_g  = (const float*)d_in[18];
    const float* bnb_b  = (const float*)d_in[19];
    const float* bnb_m  = (const float*)d_in[20];
    const float* bnb_v  = (const float*)d_in[21];
    float* out = (float*)d_out;

    // workspace layout (all chunks 16B-aligned)
    char* p = (char*)d_ws;
    int* gcur = (int*)p;                       p += (size_t)((NBIN + 3) & ~3) * 4;
    int* bcnt = (int*)p;                       p += (size_t)((NBK + 3) & ~3) * 4;
    unsigned int* binreg = (unsigned int*)p;   p += (size_t)NBIN * BINCAP * 4;
    unsigned int* sedge  = (unsigned int*)p;   p += (size_t)NBK * CAP * 4;
    unsigned short* x0  = (unsigned short*)p;  p += (size_t)NN * 32 * 2;
    unsigned short* h1  = (unsigned short*)p;  p += (size_t)NN * 64 * 2;
    unsigned short* Bp1 = (unsigned short*)p;  p += 4 * 9  * 64 * 8 * 2;
    unsigned short* Bp2 = (unsigned short*)p;  p += 4 * 18 * 64 * 8 * 2;
    float* sc1 = (float*)p;           p += 64 * 4;
    float* sh1 = (float*)p;           p += 64 * 4;
    float* sc2 = (float*)p;           p += 64 * 4;
    float* sh2 = (float*)p;           p += 64 * 4;

    // ---- two-level partition of edges (shared by both layers) ----
    hipMemsetAsync(gcur, 0, ((size_t)((NBIN + 3) & ~3) + (NBK + 3 & ~3)) * 4,
                   stream);   // zeroes gcur + bcnt (adjacent)
    binner<<<NCHUNK, 256, 0, stream>>>(ei, et, gcur, binreg);
    refine<<<NBIN * SEGS, 256, 0, stream>>>(binreg, gcur, bcnt, sedge);

    // ---- weight/bn prep ----
    prep_scales<<<1, 64, 0, stream>>>(bn64_g, bn64_b, bn64_m, bn64_v, sc1, sh1,
                                      bnb_g, bnb_b, bnb_m, bnb_v, sc2, sh2);
    pack_B<32><<<(4 * 9 * 64 + 255) / 256, 256, 0, stream>>>(W1, root1, Bp1);
    pack_B<64><<<(4 * 18 * 64 + 255) / 256, 256, 0, stream>>>(W2, root2, Bp2);

    // ---- layer 1 ----
    compute_x0<<<(NN * 16 + 255) / 256, 256, 0, stream>>>(
        n_id, emb, bn32_g, bn32_b, bn32_m, bn32_v, (unsigned int*)x0);
    fused_layer<32, true, true><<<NBK, 256, 0, stream>>>(
        x0, sedge, bcnt, Bp1, b1, sc1, sh1, h1);

    // ---- layer 2 ----
    fused_layer<64, false, false><<<NBK, 256, 0, stream>>>(
        h1, sedge, bcnt, Bp2, b2, sc2, sh2, out);
}

// Round 12
// 141.444 us; speedup vs baseline: 1.5893x; 1.0922x over previous
//
#include <hip/hip_runtime.h>

#define EPS 1e-5f
constexpr int NN  = 100000;   // nodes
constexpr int NE  = 1600000;  // edges
constexpr int R   = 8;
constexpr int NBK = NN / 16;  // 6250 dst-buckets (one per fused block)
constexpr int CAP = 512;      // bucket capacity (mean 256, sd 16)
constexpr int CHUNK  = 2048;  // edges per binner chunk
constexpr int NCHUNK = (NE + CHUNK - 1) / CHUNK;  // 782
constexpr int NBIN   = 98;    // coarse bins of 1024 nodes (64 buckets each)
constexpr int SEGS   = 9;     // refine segments per bin
constexpr int BINCAP = SEGS * CHUNK;  // 18432 (mean 16384, +16 sigma)

typedef _Float16 half8 __attribute__((ext_vector_type(8)));
typedef _Float16 h2    __attribute__((ext_vector_type(2)));
typedef float f32x4 __attribute__((ext_vector_type(4)));

static __device__ inline unsigned short f2h(float f) {
    _Float16 h = (_Float16)f;
    return __builtin_bit_cast(unsigned short, h);
}

// ---------------- x0 = bn32(emb[n_id]) -> fp16 ----------------
__global__ __launch_bounds__(256) void compute_x0(
    const int* __restrict__ n_id, const float* __restrict__ emb,
    const float* __restrict__ g, const float* __restrict__ b,
    const float* __restrict__ m, const float* __restrict__ v,
    unsigned int* __restrict__ x0)   // [NN*16] uints = [NN,32] fp16
{
    int idx = blockIdx.x * 256 + threadIdx.x;
    if (idx >= NN * 16) return;
    int i = idx >> 4, c = (idx & 15) * 2;
    int nid = n_id[i];
    float2 e = *reinterpret_cast<const float2*>(&emb[nid * 32 + c]);
    float s0 = g[c]     / sqrtf(v[c]     + EPS);
    float s1 = g[c + 1] / sqrtf(v[c + 1] + EPS);
    float y0 = (e.x - m[c])     * s0 + b[c];
    float y1 = (e.y - m[c + 1]) * s1 + b[c + 1];
    x0[idx] = (unsigned int)f2h(y0) | ((unsigned int)f2h(y1) << 16);
}

// ---------------- merged setup: zero counters + pack weights + bn scales ----
// blocks [0,24]: zero gcur+bcnt; [25,33]: pack B1; [34,51]: pack B2; 52: prep
template <int CIN>
static __device__ inline void pack_B_dev(
    int idx, const float* __restrict__ Wrel, const float* __restrict__ Wroot,
    unsigned short* __restrict__ Bp)
{
    constexpr int KS = 9 * CIN / 32;
    if (idx >= 4 * KS * 64) return;
    int l = idx & 63;
    int rest = idx >> 6;
    int s = rest % KS;
    int t = rest / KS;
    int kb = s * 32 + (l >> 4) * 8;
    int col = t * 16 + (l & 15);
    unsigned short* dst = &Bp[(size_t)idx * 8];
#pragma unroll
    for (int j = 0; j < 8; ++j) {
        int k = kb + j;
        float w = (k < CIN) ? Wroot[k * 64 + col]
                            : Wrel[(size_t)(k - CIN) * 64 + col];
        dst[j] = f2h(w);
    }
}

__global__ __launch_bounds__(256) void setup_misc(
    int* __restrict__ gcur, int* __restrict__ bcnt,
    const float* __restrict__ W1, const float* __restrict__ root1,
    unsigned short* __restrict__ Bp1,
    const float* __restrict__ W2, const float* __restrict__ root2,
    unsigned short* __restrict__ Bp2,
    const float* g1, const float* b1, const float* m1, const float* v1,
    float* sc1, float* sh1,
    const float* g2, const float* b2, const float* m2, const float* v2,
    float* sc2, float* sh2)
{
    const int blk = blockIdx.x, tid = threadIdx.x;
    if (blk < 25) {                       // zero gcur (98) + bcnt (6250)
        int i = blk * 256 + tid;
        if (i < NBIN) gcur[i] = 0;
        int j = i - NBIN;
        if (j >= 0 && j < NBK) bcnt[j] = 0;
        // blocks 0..24 cover 6400 >= 98+6250
    } else if (blk < 34) {                // pack B1: 4*9*64 = 2304 threads
        pack_B_dev<32>((blk - 25) * 256 + tid, W1, root1, Bp1);
    } else if (blk < 52) {                // pack B2: 4*18*64 = 4608 threads
        pack_B_dev<64>((blk - 34) * 256 + tid, W2, root2, Bp2);
    } else {                              // bn scale fold
        if (tid < 64) {
            int o = tid;
            float s1 = g1[o] / sqrtf(v1[o] + EPS);
            sc1[o] = s1;
            sh1[o] = b1[o] - m1[o] * s1;
            float s2 = g2[o] / sqrtf(v2[o] + EPS);
            sc2[o] = s2;
            sh2[o] = b2[o] - m2[o] * s2;
        }
    }
}

// ---------------- level 1: chunk -> coarse-bin partition (coalesced runs) ----
// payload2 = src(0-16) | r(17-19) | (dst&1023)(20-29)
__global__ __launch_bounds__(256) void binner(
    const int* __restrict__ ei, const int* __restrict__ et,
    int* __restrict__ gcur, unsigned int* __restrict__ binreg)
{
    __shared__ unsigned pay[CHUNK];
    __shared__ unsigned short bof[CHUNK];
    __shared__ unsigned srt[CHUNK];
    __shared__ unsigned short sb[CHUNK];
    __shared__ int hist[NBIN], lstart[NBIN], lcur[NBIN], gbase[NBIN];
    __shared__ int scanbuf[NBIN];

    const int tid = threadIdx.x;
    const int base = blockIdx.x * CHUNK;
    const int n = min(CHUNK, NE - base);

    for (int t = tid; t < NBIN; t += 256) hist[t] = 0;
    __syncthreads();

    for (int t = tid; t < n; t += 256) {
        int e = base + t;
        int dst = ei[NE + e];
        int bin = dst >> 10;
        pay[t] = (unsigned)ei[e] | ((unsigned)et[e] << 17) |
                 ((unsigned)(dst & 1023) << 20);
        bof[t] = (unsigned short)bin;
        atomicAdd(&hist[bin], 1);
    }
    __syncthreads();

    if (tid < NBIN) scanbuf[tid] = hist[tid];
    __syncthreads();
    for (int d = 1; d < NBIN; d <<= 1) {
        int v = 0;
        if (tid < NBIN && tid >= d) v = scanbuf[tid - d];
        __syncthreads();
        if (tid < NBIN) scanbuf[tid] += v;
        __syncthreads();
    }
    if (tid < NBIN) {
        int h = hist[tid];
        int excl = scanbuf[tid] - h;
        lstart[tid] = excl;
        lcur[tid]   = excl;
        gbase[tid]  = (h > 0) ? atomicAdd(&gcur[tid], h) : 0;
    }
    __syncthreads();

    for (int t = tid; t < n; t += 256) {
        int b = bof[t];
        int s = atomicAdd(&lcur[b], 1);
        srt[s] = pay[t];
        sb[s]  = (unsigned short)b;
    }
    __syncthreads();

    for (int s = tid; s < n; s += 256) {
        int b = sb[s];
        int pos = gbase[b] + (s - lstart[b]);
        if (pos < BINCAP)
            binreg[(size_t)b * BINCAP + pos] = srt[s];
    }
}

// ---------------- level 2: bin segment -> bucket partition ----------------
// writes fused payload = src(0-19) | r(20-22) | g(23-26) into sedge[bucket*CAP]
__global__ __launch_bounds__(256) void refine(
    const unsigned int* __restrict__ binreg, const int* __restrict__ gcur,
    int* __restrict__ bcnt, unsigned int* __restrict__ sedge)
{
    __shared__ unsigned pay[CHUNK];
    __shared__ unsigned short bof[CHUNK];
    __shared__ unsigned srt[CHUNK];
    __shared__ unsigned short sb[CHUNK];
    __shared__ int hist[64], lstart[64], lcur[64], gbase[64];
    __shared__ int scanbuf[64];

    const int tid = threadIdx.x;
    const int bin = blockIdx.x / SEGS;
    const int seg = blockIdx.x % SEGS;
    const int nbin = min(gcur[bin], BINCAP);
    const int s0 = seg * CHUNK;
    if (s0 >= nbin) return;                 // uniform per block
    const int n = min(CHUNK, nbin - s0);

    for (int t = tid; t < 64; t += 256) hist[t] = 0;
    __syncthreads();

    for (int t = tid; t < n; t += 256) {
        unsigned p = binreg[(size_t)bin * BINCAP + s0 + t];
        int bb = (p >> 24) & 63;            // (dst&1023)>>4
        pay[t] = p;
        bof[t] = (unsigned short)bb;
        atomicAdd(&hist[bb], 1);
    }
    __syncthreads();

    if (tid < 64) scanbuf[tid] = hist[tid];
    __syncthreads();
    for (int d = 1; d < 64; d <<= 1) {
        int v = 0;
        if (tid < 64 && tid >= d) v = scanbuf[tid - d];
        __syncthreads();
        if (tid < 64) scanbuf[tid] += v;
        __syncthreads();
    }
    if (tid < 64) {
        int h = hist[tid];
        int excl = scanbuf[tid] - h;
        lstart[tid] = excl;
        lcur[tid]   = excl;
        int bucket = bin * 64 + tid;
        gbase[tid] = (h > 0 && bucket < NBK) ? atomicAdd(&bcnt[bucket], h) : 0;
    }
    __syncthreads();

    for (int t = tid; t < n; t += 256) {
        int b = bof[t];
        int s = atomicAdd(&lcur[b], 1);
        srt[s] = pay[t];
        sb[s]  = (unsigned short)b;
    }
    __syncthreads();

    for (int s = tid; s < n; s += 256) {
        int bb = sb[s];
        unsigned p = srt[s];
        unsigned src = p & 0x1FFFF;
        unsigned r   = (p >> 17) & 7;
        unsigned g   = (p >> 20) & 15;
        int bucket = bin * 64 + bb;
        int pos = gbase[bb] + (s - lstart[bb]);
        if (pos < CAP)
            sedge[(size_t)bucket * CAP + pos] = src | (r << 20) | (g << 23);
    }
}

// ---------------- fused: LDS sort + split-span gather (pk_f16 run mean) + MFMA
template <int CIN, bool APPLY_RELU, bool OUT_F16>
__global__ __launch_bounds__(256) void fused_layer(
    const unsigned short* __restrict__ x,   // [N, CIN] fp16
    const unsigned int* __restrict__ sedge, // [NBK*CAP] bucketed edges
    const int* __restrict__ bcnt,           // [NBK] bucket counts
    const unsigned short* __restrict__ Bp,  // packed fp16 fragments
    const float* __restrict__ bias,         // [64]
    const float* __restrict__ scale, const float* __restrict__ shift,
    void* __restrict__ outv)                // [N,64] fp16 or fp32
{
    constexpr int NB  = 16;            // nodes per block (= MFMA M)
    constexpr int K   = 9 * CIN;       // 288 or 576
    constexpr int KS  = K / 32;        // MFMA K-steps
    constexpr int Kp  = K + 8;         // padded row stride (shorts)

    __shared__ unsigned short As[NB][Kp];
    __shared__ unsigned int   srt[CAP];
    __shared__ int cnt128[128];
    __shared__ int segoff[129];
    __shared__ int cur[128];

    const int node0 = blockIdx.x * NB;
    const int tid = threadIdx.x;
    const int nloc = min(bcnt[blockIdx.x], CAP);
    const unsigned int* sedge_b = &sedge[(size_t)blockIdx.x * CAP];

    // ---- phase 0a: zero sort counters + copy root rows + zero agg region ----
    if (tid < 128) cnt128[tid] = 0;
    for (int t = tid; t < NB * (CIN / 4); t += 256) {
        int g = t / (CIN / 4), q = (t % (CIN / 4)) * 4;
        *reinterpret_cast<uint2*>(&As[g][q]) =
            *reinterpret_cast<const uint2*>(&x[(size_t)(node0 + g) * CIN + q]);
    }
    {
        uint4 z = {0u, 0u, 0u, 0u};
        for (int t = tid; t < NB * CIN; t += 256) {
            int g = t / CIN, q = (t % CIN) * 8;
            *reinterpret_cast<uint4*>(&As[g][CIN + q]) = z;
        }
    }
    __syncthreads();

    // ---- phase 0b: count per (g,r) key (sedge read stays L2-hot) ----
    for (int t = tid; t < nloc; t += 256)
        atomicAdd(&cnt128[(sedge_b[t] >> 20) & 127], 1);
    __syncthreads();

    // ---- phase 0c: scan 128 counters (Hillis-Steele, in place) ----
    for (int d = 1; d < 128; d <<= 1) {
        int v = 0;
        if (tid < 128 && tid >= d) v = cnt128[tid - d];
        __syncthreads();
        if (tid < 128) cnt128[tid] += v;
        __syncthreads();
    }
    if (tid < 128) segoff[tid + 1] = cnt128[tid];
    if (tid == 0) segoff[0] = 0;
    __syncthreads();
    if (tid < 128) cur[tid] = segoff[tid];
    __syncthreads();

    // ---- phase 0d: place into sorted order (re-read sedge, L2-hit) ----
    for (int t = tid; t < nloc; t += 256) {
        unsigned se = sedge_b[t];
        int k = (se >> 20) & 127;
        int slot = atomicAdd(&cur[k], 1);
        srt[slot] = se;
    }
    __syncthreads();

    // ---- phase 1: half-span walk, 8-lane sub-groups, batch-8 gathers ----
    {
        const int sg   = tid >> 3;        // 32 sub-groups, 2 per node
        const int ln   = tid & 7;         // 8 lanes per sub-group
        const int g    = sg >> 1;
        const int half = sg & 1;
        const int c0   = ln * (CIN / 8);  // 8 ch/lane (CIN=64), 4 ch/lane (CIN=32)
        const int s = segoff[g * 8];
        const int e = segoff[g * 8 + 8];

        // split span at run boundary so each (g,r) bucket lives in one half
        int mm = s + ((e - s + 1) >> 1);
        if (mm > s && mm < e) {
            int rprev = (srt[mm - 1] >> 20) & 7;
            while (mm < e && (((srt[mm] >> 20) & 7) == rprev)) ++mm;
        }
        const int js = half ? mm : s;
        const int je = half ? e  : mm;

        h2 a0 = {(_Float16)0, (_Float16)0};
        h2 a1 = {(_Float16)0, (_Float16)0};
        h2 a2 = {(_Float16)0, (_Float16)0};
        h2 a3 = {(_Float16)0, (_Float16)0};
        int cur_r = -1, cnt = 0;

        auto flushrun = [&]() {
            if (cnt > 0) {
                _Float16 ih = (_Float16)(1.0f / (float)cnt);
                h2 iv = {ih, ih};
                if constexpr (CIN == 64) {
                    uint4 pk;
                    pk.x = __builtin_bit_cast(unsigned, (h2)(a0 * iv));
                    pk.y = __builtin_bit_cast(unsigned, (h2)(a1 * iv));
                    pk.z = __builtin_bit_cast(unsigned, (h2)(a2 * iv));
                    pk.w = __builtin_bit_cast(unsigned, (h2)(a3 * iv));
                    *reinterpret_cast<uint4*>(&As[g][CIN + cur_r * CIN + c0]) = pk;
                    a2 = (h2){(_Float16)0, (_Float16)0};
                    a3 = (h2){(_Float16)0, (_Float16)0};
                } else {
                    uint2 pk;
                    pk.x = __builtin_bit_cast(unsigned, (h2)(a0 * iv));
                    pk.y = __builtin_bit_cast(unsigned, (h2)(a1 * iv));
                    *reinterpret_cast<uint2*>(&As[g][CIN + cur_r * CIN + c0]) = pk;
                }
                a0 = (h2){(_Float16)0, (_Float16)0};
                a1 = (h2){(_Float16)0, (_Float16)0};
            }
        };
        auto proc = [&](unsigned se, uint4 xv) {
            int r = (int)((se >> 20) & 7);
            if (r != cur_r) { flushrun(); cur_r = r; cnt = 0; }
            a0 += __builtin_bit_cast(h2, xv.x);
            a1 += __builtin_bit_cast(h2, xv.y);
            if constexpr (CIN == 64) {
                a2 += __builtin_bit_cast(h2, xv.z);
                a3 += __builtin_bit_cast(h2, xv.w);
            }
            ++cnt;
        };
        auto loadx = [&](unsigned se) -> uint4 {
            size_t base = (size_t)(se & 0xFFFFF) * CIN + c0;
            if constexpr (CIN == 64)
                return *reinterpret_cast<const uint4*>(&x[base]);
            else {
                uint2 t2 = *reinterpret_cast<const uint2*>(&x[base]);
                return make_uint4(t2.x, t2.y, 0u, 0u);
            }
        };

        int j = js;
        for (; j + 8 <= je; j += 8) {       // batch-8: 8 gathers in flight
            unsigned se[8];
            uint4 v[8];
#pragma unroll
            for (int q = 0; q < 8; ++q) se[q] = srt[j + q];
#pragma unroll
            for (int q = 0; q < 8; ++q) v[q] = loadx(se[q]);
#pragma unroll
            for (int q = 0; q < 8; ++q) proc(se[q], v[q]);
        }
        for (; j + 4 <= je; j += 4) {
            unsigned se0 = srt[j],     se1 = srt[j + 1];
            unsigned se2 = srt[j + 2], se3 = srt[j + 3];
            uint4 v0 = loadx(se0);
            uint4 v1 = loadx(se1);
            uint4 v2 = loadx(se2);
            uint4 v3 = loadx(se3);
            proc(se0, v0); proc(se1, v1); proc(se2, v2); proc(se3, v3);
        }
        for (; j < je; ++j) {
            unsigned se0 = srt[j];
            proc(se0, loadx(se0));
        }
        flushrun();
    }
    __syncthreads();

    // ---- phase 2: [16 x K] * [K x 64] via mfma_f32_16x16x32_f16 ----
    const int lane = tid & 63, wave = tid >> 6;   // wave owns 16-col N-tile
    const int arow = lane & 15;
    const int kb   = (lane >> 4) * 8;
    f32x4 acc = {0.f, 0.f, 0.f, 0.f};
    const unsigned short* a_ptr = &As[arow][kb];
    const unsigned short* b_ptr = &Bp[((size_t)(wave * KS) * 64 + lane) * 8];
#pragma unroll
    for (int ks = 0; ks < KS; ++ks) {
        half8 a = *reinterpret_cast<const half8*>(a_ptr + ks * 32);
        half8 b = *reinterpret_cast<const half8*>(b_ptr + (size_t)ks * 64 * 8);
        acc = __builtin_amdgcn_mfma_f32_16x16x32_f16(a, b, acc, 0, 0, 0);
    }

    // ---- epilogue: bias, (relu), BN; C layout: col=lane&15, row=(lane>>4)*4+r
    const int o = wave * 16 + (lane & 15);
    const float sc = scale[o], sh = shift[o], bi = bias[o];
#pragma unroll
    for (int r = 0; r < 4; ++r) {
        int nrow = (lane >> 4) * 4 + r;
        float t = acc[r] + bi;
        if (APPLY_RELU) t = fmaxf(t, 0.0f);
        t = t * sc + sh;
        size_t oidx = (size_t)(node0 + nrow) * 64 + o;
        if (OUT_F16) ((unsigned short*)outv)[oidx] = f2h(t);
        else         ((float*)outv)[oidx] = t;
    }
}

extern "C" void kernel_launch(void* const* d_in, const int* in_sizes, int n_in,
                              void* d_out, int out_size, void* d_ws, size_t ws_size,
                              hipStream_t stream)
{
    const int*   n_id   = (const int*)d_in[0];
    const int*   ei     = (const int*)d_in[1];   // [2, NE]
    const int*   et     = (const int*)d_in[2];   // [NE]
    const float* emb    = (const float*)d_in[3];
    const float* W1     = (const float*)d_in[4];
    const float* root1  = (const float*)d_in[5];
    const float* b1     = (const float*)d_in[6];
    const float* W2     = (const float*)d_in[7];
    const float* root2  = (const float*)d_in[8];
    const float* b2     = (const float*)d_in[9];
    const float* bn32_g = (const float*)d_in[10];
    const float* bn32_b = (const float*)d_in[11];
    const float* bn32_m = (const float*)d_in[12];
    const float* bn32_v = (const float*)d_in[13];
    const float* bn64_g = (const float*)d_in[14];
    const float* bn64_b = (const float*)d_in[15];
    const float* bn64_m = (const float*)d_in[16];
    const float* bn64_v = (const float*)d_in[17];
    const float* bnb_g  = (const float*)d_in[18];
    const float* bnb_b  = (const float*)d_in[19];
    const float* bnb_m  = (const float*)d_in[20];
    const float* bnb_v  = (const float*)d_in[21];
    float* out = (float*)d_out;

    // workspace layout (all chunks 16B-aligned)
    char* p = (char*)d_ws;
    int* gcur = (int*)p;                       p += (size_t)((NBIN + 3) & ~3) * 4;
    int* bcnt = (int*)p;                       p += (size_t)((NBK + 3) & ~3) * 4;
    unsigned int* binreg = (unsigned int*)p;   p += (size_t)NBIN * BINCAP * 4;
    unsigned int* sedge  = (unsigned int*)p;   p += (size_t)NBK * CAP * 4;
    unsigned short* x0  = (unsigned short*)p;  p += (size_t)NN * 32 * 2;
    unsigned short* h1  = (unsigned short*)p;  p += (size_t)NN * 64 * 2;
    unsigned short* Bp1 = (unsigned short*)p;  p += 4 * 9  * 64 * 8 * 2;
    unsigned short* Bp2 = (unsigned short*)p;  p += 4 * 18 * 64 * 8 * 2;
    float* sc1 = (float*)p;           p += 64 * 4;
    float* sh1 = (float*)p;           p += 64 * 4;
    float* sc2 = (float*)p;           p += 64 * 4;
    float* sh2 = (float*)p;           p += 64 * 4;

    // ---- merged setup (zero counters, pack weights, bn scales) ----
    setup_misc<<<53, 256, 0, stream>>>(gcur, bcnt, W1, root1, Bp1,
                                       W2, root2, Bp2,
                                       bn64_g, bn64_b, bn64_m, bn64_v, sc1, sh1,
                                       bnb_g, bnb_b, bnb_m, bnb_v, sc2, sh2);

    // ---- two-level partition of edges (shared by both layers) ----
    binner<<<NCHUNK, 256, 0, stream>>>(ei, et, gcur, binreg);
    refine<<<NBIN * SEGS, 256, 0, stream>>>(binreg, gcur, bcnt, sedge);

    // ---- layer 1 ----
    compute_x0<<<(NN * 16 + 255) / 256, 256, 0, stream>>>(
        n_id, emb, bn32_g, bn32_b, bn32_m, bn32_v, (unsigned int*)x0);
    fused_layer<32, true, true><<<NBK, 256, 0, stream>>>(
        x0, sedge, bcnt, Bp1, b1, sc1, sh1, h1);

    // ---- layer 2 ----
    fused_layer<64, false, false><<<NBK, 256, 0, stream>>>(
        h1, sedge, bcnt, Bp2, b2, sc2, sh2, out);
}